// Round 7
// baseline (5164.462 us; speedup 1.0000x reference)
//
#include <hip/hip_runtime.h>

#define N_TOTAL 150000
#define N_PAD 150016            // 256*586
#define DIM 128
#define NNZ_E 1500000
#define NBUCK 256
#define DPB 586                 // dests per bucket: 256*586 = 150016 >= 150000
#define EPB2 2048               // edges per fused phase-A block (emits 2 entries each)
#define A2_BLOCKS ((NNZ_E + EPB2 - 1) / EPB2)   // 733
#define CONV_BLOCKS 9375        // N_TOTAL*DIM/8 / 256
#define HIST_BLOCKS 512
#define KPAD 20                 // padded slots/row (Poisson(10): P(n>20)~0.16%)
#define OVF_CAP 8192

typedef unsigned long long u64;
typedef unsigned uvec16 __attribute__((ext_vector_type(16)));
typedef unsigned uvec8  __attribute__((ext_vector_type(8)));

// ---------- bf16 pack/unpack (RNE) ----------
__device__ __forceinline__ unsigned pack_bf16_bits(unsigned ua, unsigned ub) {
    ua = (ua + 0x7FFFu + ((ua >> 16) & 1u)) >> 16;
    ub = (ub + 0x7FFFu + ((ub >> 16) & 1u)) >> 16;
    return ua | (ub << 16);
}
__device__ __forceinline__ unsigned pack_bf16(float a, float b) {
    return pack_bf16_bits(__float_as_uint(a), __float_as_uint(b));
}
__device__ __forceinline__ float2 unpack_bf16(unsigned u) {
    return make_float2(__uint_as_float(u << 16), __uint_as_float(u & 0xFFFF0000u));
}
__device__ __forceinline__ float rdlane_f(float x, int l) {
    return __uint_as_float((unsigned)__builtin_amdgcn_readlane((int)__float_as_uint(x), l));
}

// ---------- one parallel scalar-load batch: full 160B padded row ----------
__device__ __forceinline__ void sload_row(uvec16 &a, uvec16 &b, uvec8 &c, const void* p) {
    asm volatile("s_load_dwordx16 %0, %3, 0x0\n\t"
                 "s_load_dwordx16 %1, %3, 0x40\n\t"
                 "s_load_dwordx8 %2, %3, 0x80\n\t"
                 "s_waitcnt lgkmcnt(0)"
                 : "=&s"(a), "=&s"(b), "=&s"(c) : "s"(p) : "memory");
}

// process 8 edges from an SGPR chunk; lim = valid count (scalar).
// Speculative slots: index AND weight gated scalar-side (s_cselect) -> invalid
// slots load row 0 (L1-hot). Loads stay branchless -> batch issues in parallel.
__device__ __forceinline__ void chunk8(const uvec16 &m, int lim, int lane,
                                       const uint* __restrict__ srcBf,
                                       float &ax, float &ay, float &bx, float &by) {
    #pragma unroll
    for (int j = 0; j < 8; j++) {
        unsigned sx = (j < lim) ? (m[2 * j] & 0x3FFFFu) : 0u;
        float vv = (j < lim) ? __uint_as_float(m[2 * j + 1]) : 0.0f;
        const uint* p = srcBf + ((size_t)sx << 6);   // uniform base -> saddr load
        float2 uu = unpack_bf16(p[lane]);
        if (j & 1) { bx += vv * uu.x; by += vv * uu.y; }
        else       { ax += vv * uu.x; ay += vv * uu.y; }
    }
}
__device__ __forceinline__ void chunk4(const uvec8 &m, int lim, int lane,
                                       const uint* __restrict__ srcBf,
                                       float &ax, float &ay, float &bx, float &by) {
    #pragma unroll
    for (int j = 0; j < 4; j++) {
        unsigned sx = (j < lim) ? (m[2 * j] & 0x3FFFFu) : 0u;
        float vv = (j < lim) ? __uint_as_float(m[2 * j + 1]) : 0.0f;
        const uint* p = srcBf + ((size_t)sx << 6);
        float2 uu = unpack_bf16(p[lane]);
        if (j & 1) { bx += vv * uu.x; by += vv * uu.y; }
        else       { ax += vv * uu.x; ay += vv * uu.y; }
    }
}

// ---------- fused: ego fp32 -> bf16 (blocks < CONV_BLOCKS) || coarse hist ----------
__global__ __launch_bounds__(256) void conv_hist(const float* __restrict__ in,
                                                 uint* __restrict__ outp,
                                                 const int* __restrict__ rows,
                                                 const int* __restrict__ cols,
                                                 int* __restrict__ cnt1,
                                                 int* __restrict__ cnt2) {
    __shared__ int h[512];
    int t = threadIdx.x;
    if (blockIdx.x < CONV_BLOCKS) {
        int i = blockIdx.x * 256 + t;                // exactly N*D/8 threads
        const u64* in8 = (const u64*)in;
        u64 w0 = __builtin_nontemporal_load(&in8[4 * i + 0]);
        u64 w1 = __builtin_nontemporal_load(&in8[4 * i + 1]);
        u64 w2 = __builtin_nontemporal_load(&in8[4 * i + 2]);
        u64 w3 = __builtin_nontemporal_load(&in8[4 * i + 3]);
        uint4 o;
        o.x = pack_bf16_bits((unsigned)w0, (unsigned)(w0 >> 32));
        o.y = pack_bf16_bits((unsigned)w1, (unsigned)(w1 >> 32));
        o.z = pack_bf16_bits((unsigned)w2, (unsigned)(w2 >> 32));
        o.w = pack_bf16_bits((unsigned)w3, (unsigned)(w3 >> 32));
        ((uint4*)outp)[i] = o;
    } else {
        h[t] = 0; h[t + 256] = 0;
        __syncthreads();
        int bid = blockIdx.x - CONV_BLOCKS;
        int stride = HIST_BLOCKS * 256;
        for (int e = bid * 256 + t; e < NNZ_E; e += stride) {
            atomicAdd(&h[cols[e] / DPB], 1);          // pass-1 dest = col
            atomicAdd(&h[256 + rows[e] / DPB], 1);    // pass-2 dest = row
        }
        __syncthreads();
        if (h[t]) atomicAdd(&cnt1[t], h[t]);
        if (h[t + 256]) atomicAdd(&cnt2[t], h[t + 256]);
    }
}

// ---------- scan 512 bucket counts -> slab bases sb[513]; zero cursors ----------
__global__ __launch_bounds__(256) void scan_buckets(const int* __restrict__ cnt,
                                                    int* __restrict__ sb,
                                                    int* __restrict__ gc) {
    __shared__ int buf[256];
    int t = threadIdx.x;
    int v = cnt[t]; buf[t] = v; __syncthreads();
    for (int o = 1; o < 256; o <<= 1) {
        int a = (t >= o) ? buf[t - o] : 0; __syncthreads();
        buf[t] += a; __syncthreads();
    }
    sb[t] = buf[t] - v;               // pass-1 region: [0, NNZ)
    __syncthreads();
    int v2 = cnt[256 + t]; buf[t] = v2; __syncthreads();
    for (int o = 1; o < 256; o <<= 1) {
        int a = (t >= o) ? buf[t - o] : 0; __syncthreads();
        buf[t] += a; __syncthreads();
    }
    sb[256 + t] = NNZ_E + buf[t] - v2;  // pass-2 region: [NNZ, 2*NNZ)
    if (t == 255) sb[512] = 2 * NNZ_E;
    gc[t] = 0; gc[256 + t] = 0;
}

// ---------- fused phase A: bin 2048 edges -> 4096 entries over 512 buckets ----------
__global__ __launch_bounds__(256) void phaseA_fused(const int* __restrict__ rows,
                                                    const int* __restrict__ cols,
                                                    const float* __restrict__ vals,
                                                    const int* __restrict__ slabBase,
                                                    int* __restrict__ gCur,
                                                    uint2* __restrict__ slab) {
    __shared__ uint2 sortedL[2 * EPB2];          // 32 KB
    __shared__ unsigned short bktL[2 * EPB2];    // 8 KB
    __shared__ int cnt[512], off[512], cur[512], gbase[512];   // 8 KB
    __shared__ int part[256];                    // 1 KB
    __shared__ int totE;
    int t = threadIdx.x;
    int base = blockIdx.x * EPB2;
    cnt[t] = 0; cnt[t + 256] = 0;
    __syncthreads();

    uint2 eA[8], eB[8];
    short bA[8], bB[8];
    #pragma unroll
    for (int j = 0; j < 8; j++) {
        int e = base + j * 256 + t;
        if (e < NNZ_E) {
            int r = rows[e], c = cols[e];
            unsigned v = __float_as_uint(vals[e]);
            int b1 = c / DPB, dl1 = c - b1 * DPB;     // pass-1 dest = col, src = row
            int b2 = r / DPB, dl2 = r - b2 * DPB;     // pass-2 dest = row, src = col
            bA[j] = (short)b1;
            eA[j].x = ((unsigned)dl1 << 18) | (unsigned)r;
            eA[j].y = v;
            bB[j] = (short)(256 + b2);
            eB[j].x = ((unsigned)dl2 << 18) | (unsigned)c;
            eB[j].y = v;
            atomicAdd(&cnt[b1], 1);
            atomicAdd(&cnt[256 + b2], 1);
        } else { bA[j] = -1; bB[j] = -1; }
    }
    __syncthreads();
    // scan 512 counts (2 per thread) -> exclusive off/cur
    int c0 = cnt[2 * t], c1 = cnt[2 * t + 1];
    int ps = c0 + c1;
    part[t] = ps; __syncthreads();
    for (int o = 1; o < 256; o <<= 1) {
        int a = (t >= o) ? part[t - o] : 0; __syncthreads();
        part[t] += a; __syncthreads();
    }
    int bs = part[t] - ps;
    off[2 * t] = bs;          cur[2 * t] = bs;
    off[2 * t + 1] = bs + c0; cur[2 * t + 1] = bs + c0;
    if (t == 255) totE = part[255];
    __syncthreads();
    // bucket-sorted scatter into LDS (both entries per edge)
    #pragma unroll
    for (int j = 0; j < 8; j++) {
        if (bA[j] >= 0) {
            int p = atomicAdd(&cur[(int)bA[j]], 1);
            sortedL[p] = eA[j]; bktL[p] = (unsigned short)bA[j];
            p = atomicAdd(&cur[(int)bB[j]], 1);
            sortedL[p] = eB[j]; bktL[p] = (unsigned short)bB[j];
        }
    }
    __syncthreads();
    // reserve global slab space, one atomic per non-empty bucket
    for (int b = t; b < 512; b += 256) {
        int n = cnt[b];
        if (n > 0) gbase[b] = atomicAdd(&gCur[b], n);
    }
    __syncthreads();
    int nE = totE;
    for (int i = t; i < nE; i += 256) {
        int b = bktL[i];
        slab[slabBase[b] + gbase[b] + (i - off[b])] = sortedL[i];
    }
}

// ---------- phase B (per direction): slab bucket -> padded per-row table ----------
// srt row dd: KPAD uint2 slots; slot0.x bits 27-31 = min(count,31); overflow -> ovf.
__global__ __launch_bounds__(512) void phaseB_pad(const uint2* __restrict__ slab,
                                                  const int* __restrict__ slabBase,
                                                  int bucketBase,
                                                  uint2* __restrict__ srt,
                                                  int* __restrict__ ovfCnt,
                                                  uint4* __restrict__ ovf) {
    __shared__ int cur[DPB];
    int t = threadIdx.x;
    int b = blockIdx.x + bucketBase;
    int s0 = slabBase[b], se = slabBase[b + 1];
    int n = se - s0;
    for (int d = t; d < DPB; d += 512) cur[d] = 0;
    __syncthreads();
    int destBase = blockIdx.x * DPB;
    for (int i = t; i < n; i += 512) {
        uint2 e = slab[s0 + i];
        int dl = e.x >> 18;
        int p = atomicAdd(&cur[dl], 1);
        if (p < KPAD) {
            srt[(size_t)(destBase + dl) * KPAD + p] = make_uint2(e.x & 0x3FFFFu, e.y);
        } else {
            int o = atomicAdd(ovfCnt, 1);
            if (o < OVF_CAP) ovf[o] = make_uint4((unsigned)(destBase + dl),
                                                 e.x & 0x3FFFFu, e.y, 0u);
        }
    }
    __syncthreads();     // drains vmcnt -> scatter stores are in L2 before fixup
    for (int d = t; d < DPB; d += 512) {
        int dd = destBase + d;
        int c = cur[d];
        size_t p0 = (size_t)dd * KPAD;
        if (c == 0) {
            srt[p0] = make_uint2(0u, 0u);            // stale row -> nenc=0
        } else {
            unsigned nenc = (unsigned)(c > 31 ? 31 : c) << 27;
            __hip_atomic_fetch_or((unsigned*)&srt[p0].x, nenc,
                                  __ATOMIC_RELAXED, __HIP_MEMORY_SCOPE_AGENT);
        }
    }
}

// ---------- gather 1: one s_load batch per row (no dependent chain) ----------
__global__ __launch_bounds__(256) void gather1(const uint* __restrict__ srcBf,
                                               const uint2* __restrict__ srt,
                                               const int* __restrict__ ovfCnt,
                                               const uint4* __restrict__ ovf,
                                               uint* __restrict__ dstBf) {
    int lane = threadIdx.x & 63;
    int row = blockIdx.x * 4 + (threadIdx.x >> 6);      // grid covers exactly N_TOTAL
    int row_u = __builtin_amdgcn_readfirstlane(row);
    uvec16 mA, mB; uvec8 mC;
    sload_row(mA, mB, mC, srt + (size_t)row_u * KPAD);
    int n = (int)(mA[0] >> 27);
    float ax = 0.f, ay = 0.f, bx = 0.f, by = 0.f;
    chunk8(mA, n < 8 ? n : 8, lane, srcBf, ax, ay, bx, by);
    if (n > 8) {
        chunk8(mB, n - 8 < 8 ? n - 8 : 8, lane, srcBf, ax, ay, bx, by);
        if (n > 16) {
            chunk4(mC, n - 16 < 4 ? n - 16 : 4, lane, srcBf, ax, ay, bx, by);
            if (n > KPAD) {                             // rare: ~0.16% of rows
                int oc = *ovfCnt; oc = oc < OVF_CAP ? oc : OVF_CAP;
                for (int i = 0; i < oc; i++) {
                    uint4 e = ovf[i];
                    if (e.x == (unsigned)row_u) {
                        float v = __uint_as_float(e.z);
                        float2 u = unpack_bf16(srcBf[(((size_t)e.y) << 6) + lane]);
                        ax += v * u.x; ay += v * u.y;
                    }
                }
            }
        }
    }
    dstBf[(size_t)row_u * 64 + lane] = pack_bf16(ax + bx, ay + by);
}

// ---------- gather 2 + LN + residual ----------
__global__ __launch_bounds__(256) void gather2_ln(const uint* __restrict__ hBf,
                                                  const uint2* __restrict__ srt,
                                                  const int* __restrict__ ovfCnt,
                                                  const uint4* __restrict__ ovf,
                                                  const uint* __restrict__ egoBf,
                                                  const float* __restrict__ gamma,
                                                  const float* __restrict__ beta,
                                                  float* __restrict__ out) {
    int lane = threadIdx.x & 63;
    int row = blockIdx.x * 4 + (threadIdx.x >> 6);
    int row_u = __builtin_amdgcn_readfirstlane(row);
    uvec16 mA, mB; uvec8 mC;
    sload_row(mA, mB, mC, srt + (size_t)row_u * KPAD);
    int n = (int)(mA[0] >> 27);
    float ax = 0.f, ay = 0.f, bx = 0.f, by = 0.f;
    chunk8(mA, n < 8 ? n : 8, lane, hBf, ax, ay, bx, by);
    if (n > 8) {
        chunk8(mB, n - 8 < 8 ? n - 8 : 8, lane, hBf, ax, ay, bx, by);
        if (n > 16) {
            chunk4(mC, n - 16 < 4 ? n - 16 : 4, lane, hBf, ax, ay, bx, by);
            if (n > KPAD) {
                int oc = *ovfCnt; oc = oc < OVF_CAP ? oc : OVF_CAP;
                for (int i = 0; i < oc; i++) {
                    uint4 e = ovf[i];
                    if (e.x == (unsigned)row_u) {
                        float v = __uint_as_float(e.z);
                        float2 u = unpack_bf16(hBf[(((size_t)e.y) << 6) + lane]);
                        ax += v * u.x; ay += v * u.y;
                    }
                }
            }
        }
    }
    float2 acc = make_float2(ax + bx, ay + by);
    float s = acc.x + acc.y;
    float sq = acc.x * acc.x + acc.y * acc.y;
    #pragma unroll
    for (int o = 1; o <= 16; o <<= 1) {
        s  += __shfl_xor(s, o, 64);
        sq += __shfl_xor(sq, o, 64);
    }
    float sT  = rdlane_f(s, 0)  + rdlane_f(s, 32);
    float sqT = rdlane_f(sq, 0) + rdlane_f(sq, 32);
    float mu = sT * (1.0f / DIM);
    float var = sqT * (1.0f / DIM) - mu * mu;
    float rs = rsqrtf(var + 1e-5f);
    float2 g  = ((const float2*)gamma)[lane];
    float2 bb = ((const float2*)beta)[lane];
    unsigned egoW = __builtin_nontemporal_load(&egoBf[(size_t)row_u * 64 + lane]);
    float2 e2 = unpack_bf16(egoW);
    float2 o2;
    o2.x = (acc.x - mu) * rs * g.x + bb.x + e2.x;
    o2.y = (acc.y - mu) * rs * g.y + bb.y + e2.y;
    u64 ow = (u64)__float_as_uint(o2.x) | ((u64)__float_as_uint(o2.y) << 32);
    __builtin_nontemporal_store(ow, (u64*)out + (size_t)row_u * 64 + lane);
}

// ---------- fallback: atomic scatter path (ws too small) ----------
__device__ __forceinline__ void atomic_add_f32(float* p, float v) {
    __hip_atomic_fetch_add(p, v, __ATOMIC_RELAXED, __HIP_MEMORY_SCOPE_AGENT);
}
__global__ void scatter_kernel(const float* __restrict__ src, const float* __restrict__ vals,
                               const int* __restrict__ gidx, const int* __restrict__ sidx,
                               float* __restrict__ dst, int nnz) {
    int gid = blockIdx.x * blockDim.x + threadIdx.x;
    int e = gid >> 5, lane = gid & 31;
    if (e >= nnz) return;
    float v = vals[e];
    float4 x = ((const float4*)(src + (size_t)gidx[e] * DIM))[lane];
    float* d = dst + (size_t)sidx[e] * DIM + lane * 4;
    atomic_add_f32(d + 0, v * x.x); atomic_add_f32(d + 1, v * x.y);
    atomic_add_f32(d + 2, v * x.z); atomic_add_f32(d + 3, v * x.w);
}
__global__ void ln_residual_kernel(const float* __restrict__ h2, const float* __restrict__ ego,
                                   const float* __restrict__ gamma, const float* __restrict__ beta,
                                   float* __restrict__ out, int nrows) {
    int gid = blockIdx.x * blockDim.x + threadIdx.x;
    int row = gid >> 6, lane = gid & 63;
    if (row >= nrows) return;
    float2 x = ((const float2*)(h2 + (size_t)row * DIM))[lane];
    float s = x.x + x.y, sq = x.x * x.x + x.y * x.y;
    #pragma unroll
    for (int o = 32; o > 0; o >>= 1) { s += __shfl_xor(s, o, 64); sq += __shfl_xor(sq, o, 64); }
    float mu = s * (1.0f / DIM), var = sq * (1.0f / DIM) - mu * mu;
    float rs = rsqrtf(var + 1e-5f);
    float2 eg = ((const float2*)(ego + (size_t)row * DIM))[lane];
    float2 g = ((const float2*)gamma)[lane], b = ((const float2*)beta)[lane];
    float2 o2;
    o2.x = (x.x - mu) * rs * g.x + b.x + eg.x;
    o2.y = (x.y - mu) * rs * g.y + b.y + eg.y;
    ((float2*)(out + (size_t)row * DIM))[lane] = o2;
}

// ---------- launch ----------
extern "C" void kernel_launch(void* const* d_in, const int* in_sizes, int n_in,
                              void* d_out, int out_size, void* d_ws, size_t ws_size,
                              hipStream_t stream) {
    const float* ego   = (const float*)d_in[0];
    const float* vals  = (const float*)d_in[1];
    const float* gamma = (const float*)d_in[2];
    const float* beta  = (const float*)d_in[3];
    const int*   rows  = (const int*)d_in[4];
    const int*   cols  = (const int*)d_in[5];
    float* out = (float*)d_out;

    const size_t EGO_BF_B = (size_t)N_TOTAL * DIM * 2;               // 38.4 MB
    const size_t H_BF_B   = (size_t)N_TOTAL * DIM * 2;               // 38.4 MB
    const size_t SRT_B    = (size_t)N_PAD * KPAD * sizeof(uint2);    // 24.0 MB
    const size_t OVF_B    = (size_t)OVF_CAP * 16;                    // 128 KB each
    const size_t REQ = EGO_BF_B + H_BF_B + SRT_B + 8192 + 2 * OVF_B; // ~101.2 MB
    const size_t H_FP32_B = (size_t)N_TOTAL * DIM * sizeof(float);   // fallback: 76.8 MB

    char* w = (char*)d_ws;
    uint* egoBf   = (uint*)w;   w += EGO_BF_B;
    uint* hBf     = (uint*)w;   w += H_BF_B;
    uint2* srt    = (uint2*)w;  w += SRT_B;
    int* cntArr   = (int*)w;    w += 512 * sizeof(int);
    int* ovfc     = (int*)w;    w += 64 * sizeof(int);   // [0]=dir1, [32]=dir2
    int* sb       = (int*)w;    w += 516 * sizeof(int);
    int* gc       = (int*)w;    w += 512 * sizeof(int);
    uint4* ovf1   = (uint4*)w;  w += OVF_B;
    uint4* ovf2   = (uint4*)w;  w += OVF_B;
    uint2* slab   = (uint2*)d_out;       // 24 MB scratch; dead before gather2 writes out

    if (ws_size >= REQ && (size_t)out_size >= (size_t)2 * NNZ_E * sizeof(uint2)) {
        (void)hipMemsetAsync(cntArr, 0, (512 + 64) * sizeof(int), stream);
        conv_hist<<<CONV_BLOCKS + HIST_BLOCKS, 256, 0, stream>>>(ego, egoBf, rows, cols,
                                                                 cntArr, cntArr + 256);
        scan_buckets<<<1, 256, 0, stream>>>(cntArr, sb, gc);
        phaseA_fused<<<A2_BLOCKS, 256, 0, stream>>>(rows, cols, vals, sb, gc, slab);

        int ggrid = (N_TOTAL + 3) / 4;      // 4 waves/block, 1 row/wave -> 37500
        phaseB_pad<<<NBUCK, 512, 0, stream>>>(slab, sb, 0, srt, ovfc, ovf1);
        gather1<<<ggrid, 256, 0, stream>>>(egoBf, srt, ovfc, ovf1, hBf);
        phaseB_pad<<<NBUCK, 512, 0, stream>>>(slab, sb, 256, srt, ovfc + 32, ovf2);
        gather2_ln<<<ggrid, 256, 0, stream>>>(hBf, srt, ovfc + 32, ovf2,
                                              egoBf, gamma, beta, out);
    } else {
        float* h = (float*)d_ws;            // fallback: fp32 h at ws start
        (void)hipMemsetAsync(h, 0, H_FP32_B, stream);
        (void)hipMemsetAsync(out, 0, H_FP32_B, stream);
        long total = (long)NNZ_E * 32;
        int grid = (int)((total + 255) / 256);
        scatter_kernel<<<grid, 256, 0, stream>>>(ego, vals, rows, cols, h, NNZ_E);
        scatter_kernel<<<grid, 256, 0, stream>>>(h, vals, cols, rows, out, NNZ_E);
        int lngrid = (N_TOTAL * 64 + 255) / 256;
        ln_residual_kernel<<<lngrid, 256, 0, stream>>>(out, ego, gamma, beta, out, N_TOTAL);
    }
}

// Round 8
// 425.269 us; speedup vs baseline: 12.1440x; 12.1440x over previous
//
#include <hip/hip_runtime.h>

#define N_TOTAL 150000
#define N_PAD 150016            // 256*586
#define DIM 128
#define NNZ_E 1500000
#define NBUCK 256
#define DPB 586                 // dests per bucket: 256*586 = 150016 >= 150000
#define EPB2 2048               // edges per fused phase-A block (emits 2 entries each)
#define A2_BLOCKS ((NNZ_E + EPB2 - 1) / EPB2)   // 733
#define CONV_BLOCKS 9375        // N_TOTAL*DIM/8 / 256
#define HIST_BLOCKS 512
#define KPAD 20                 // padded slots/row (Poisson(10): P(n>20)~0.16%)
#define OVF_CAP 8192

typedef unsigned long long u64;
typedef unsigned uvec16 __attribute__((ext_vector_type(16)));
typedef unsigned uvec8  __attribute__((ext_vector_type(8)));

// ---------- bf16 pack/unpack (RNE) ----------
__device__ __forceinline__ unsigned pack_bf16_bits(unsigned ua, unsigned ub) {
    ua = (ua + 0x7FFFu + ((ua >> 16) & 1u)) >> 16;
    ub = (ub + 0x7FFFu + ((ub >> 16) & 1u)) >> 16;
    return ua | (ub << 16);
}
__device__ __forceinline__ unsigned pack_bf16(float a, float b) {
    return pack_bf16_bits(__float_as_uint(a), __float_as_uint(b));
}
__device__ __forceinline__ float2 unpack_bf16(unsigned u) {
    return make_float2(__uint_as_float(u << 16), __uint_as_float(u & 0xFFFF0000u));
}
__device__ __forceinline__ float rdlane_f(float x, int l) {
    return __uint_as_float((unsigned)__builtin_amdgcn_readlane((int)__float_as_uint(x), l));
}

// ---------- one parallel scalar-load batch: full 160B padded row ----------
__device__ __forceinline__ void sload_row(uvec16 &a, uvec16 &b, uvec8 &c, const void* p) {
    asm volatile("s_load_dwordx16 %0, %3, 0x0\n\t"
                 "s_load_dwordx16 %1, %3, 0x40\n\t"
                 "s_load_dwordx8 %2, %3, 0x80\n\t"
                 "s_waitcnt lgkmcnt(0)"
                 : "=&s"(a), "=&s"(b), "=&s"(c) : "s"(p) : "memory");
}

// process 8 edges from an SGPR chunk; lim = valid count (scalar).
// Speculative slots: index AND weight gated scalar-side (s_cselect) -> invalid
// slots load row 0 (L1-hot). Loads stay branchless -> batch issues in parallel.
__device__ __forceinline__ void chunk8(const uvec16 &m, int lim, int lane,
                                       const uint* __restrict__ srcBf,
                                       float &ax, float &ay, float &bx, float &by) {
    #pragma unroll
    for (int j = 0; j < 8; j++) {
        unsigned sx = (j < lim) ? (m[2 * j] & 0x3FFFFu) : 0u;
        float vv = (j < lim) ? __uint_as_float(m[2 * j + 1]) : 0.0f;
        const uint* p = srcBf + ((size_t)sx << 6);   // uniform base -> saddr load
        float2 uu = unpack_bf16(p[lane]);
        if (j & 1) { bx += vv * uu.x; by += vv * uu.y; }
        else       { ax += vv * uu.x; ay += vv * uu.y; }
    }
}
__device__ __forceinline__ void chunk4(const uvec8 &m, int lim, int lane,
                                       const uint* __restrict__ srcBf,
                                       float &ax, float &ay, float &bx, float &by) {
    #pragma unroll
    for (int j = 0; j < 4; j++) {
        unsigned sx = (j < lim) ? (m[2 * j] & 0x3FFFFu) : 0u;
        float vv = (j < lim) ? __uint_as_float(m[2 * j + 1]) : 0.0f;
        const uint* p = srcBf + ((size_t)sx << 6);
        float2 uu = unpack_bf16(p[lane]);
        if (j & 1) { bx += vv * uu.x; by += vv * uu.y; }
        else       { ax += vv * uu.x; ay += vv * uu.y; }
    }
}

// ---------- fused: ego fp32 -> bf16 (blocks < CONV_BLOCKS) || coarse hist ----------
__global__ __launch_bounds__(256) void conv_hist(const float* __restrict__ in,
                                                 uint* __restrict__ outp,
                                                 const int* __restrict__ rows,
                                                 const int* __restrict__ cols,
                                                 int* __restrict__ cnt1,
                                                 int* __restrict__ cnt2) {
    __shared__ int h[512];
    int t = threadIdx.x;
    if (blockIdx.x < CONV_BLOCKS) {
        int i = blockIdx.x * 256 + t;                // exactly N*D/8 threads
        const u64* in8 = (const u64*)in;
        u64 w0 = __builtin_nontemporal_load(&in8[4 * i + 0]);
        u64 w1 = __builtin_nontemporal_load(&in8[4 * i + 1]);
        u64 w2 = __builtin_nontemporal_load(&in8[4 * i + 2]);
        u64 w3 = __builtin_nontemporal_load(&in8[4 * i + 3]);
        uint4 o;
        o.x = pack_bf16_bits((unsigned)w0, (unsigned)(w0 >> 32));
        o.y = pack_bf16_bits((unsigned)w1, (unsigned)(w1 >> 32));
        o.z = pack_bf16_bits((unsigned)w2, (unsigned)(w2 >> 32));
        o.w = pack_bf16_bits((unsigned)w3, (unsigned)(w3 >> 32));
        ((uint4*)outp)[i] = o;
    } else {
        h[t] = 0; h[t + 256] = 0;
        __syncthreads();
        int bid = blockIdx.x - CONV_BLOCKS;
        int stride = HIST_BLOCKS * 256;
        for (int e = bid * 256 + t; e < NNZ_E; e += stride) {
            atomicAdd(&h[cols[e] / DPB], 1);          // pass-1 dest = col
            atomicAdd(&h[256 + rows[e] / DPB], 1);    // pass-2 dest = row
        }
        __syncthreads();
        if (h[t]) atomicAdd(&cnt1[t], h[t]);
        if (h[t + 256]) atomicAdd(&cnt2[t], h[t + 256]);
    }
}

// ---------- scan 512 bucket counts -> slab bases sb[513]; zero cursors ----------
__global__ __launch_bounds__(256) void scan_buckets(const int* __restrict__ cnt,
                                                    int* __restrict__ sb,
                                                    int* __restrict__ gc) {
    __shared__ int buf[256];
    int t = threadIdx.x;
    int v = cnt[t]; buf[t] = v; __syncthreads();
    for (int o = 1; o < 256; o <<= 1) {
        int a = (t >= o) ? buf[t - o] : 0; __syncthreads();
        buf[t] += a; __syncthreads();
    }
    sb[t] = buf[t] - v;               // pass-1 region: [0, NNZ)
    __syncthreads();
    int v2 = cnt[256 + t]; buf[t] = v2; __syncthreads();
    for (int o = 1; o < 256; o <<= 1) {
        int a = (t >= o) ? buf[t - o] : 0; __syncthreads();
        buf[t] += a; __syncthreads();
    }
    sb[256 + t] = NNZ_E + buf[t] - v2;  // pass-2 region: [NNZ, 2*NNZ)
    if (t == 255) sb[512] = 2 * NNZ_E;
    gc[t] = 0; gc[256 + t] = 0;
}

// ---------- fused phase A: bin 2048 edges -> 4096 entries over 512 buckets ----------
__global__ __launch_bounds__(256) void phaseA_fused(const int* __restrict__ rows,
                                                    const int* __restrict__ cols,
                                                    const float* __restrict__ vals,
                                                    const int* __restrict__ slabBase,
                                                    int* __restrict__ gCur,
                                                    uint2* __restrict__ slab) {
    __shared__ uint2 sortedL[2 * EPB2];          // 32 KB
    __shared__ unsigned short bktL[2 * EPB2];    // 8 KB
    __shared__ int cnt[512], off[512], cur[512], gbase[512];   // 8 KB
    __shared__ int part[256];                    // 1 KB
    __shared__ int totE;
    int t = threadIdx.x;
    int base = blockIdx.x * EPB2;
    cnt[t] = 0; cnt[t + 256] = 0;
    __syncthreads();

    uint2 eA[8], eB[8];
    short bA[8], bB[8];
    #pragma unroll
    for (int j = 0; j < 8; j++) {
        int e = base + j * 256 + t;
        if (e < NNZ_E) {
            int r = rows[e], c = cols[e];
            unsigned v = __float_as_uint(vals[e]);
            int b1 = c / DPB, dl1 = c - b1 * DPB;     // pass-1 dest = col, src = row
            int b2 = r / DPB, dl2 = r - b2 * DPB;     // pass-2 dest = row, src = col
            bA[j] = (short)b1;
            eA[j].x = ((unsigned)dl1 << 18) | (unsigned)r;
            eA[j].y = v;
            bB[j] = (short)(256 + b2);
            eB[j].x = ((unsigned)dl2 << 18) | (unsigned)c;
            eB[j].y = v;
            atomicAdd(&cnt[b1], 1);
            atomicAdd(&cnt[256 + b2], 1);
        } else { bA[j] = -1; bB[j] = -1; }
    }
    __syncthreads();
    // scan 512 counts (2 per thread) -> exclusive off/cur
    int c0 = cnt[2 * t], c1 = cnt[2 * t + 1];
    int ps = c0 + c1;
    part[t] = ps; __syncthreads();
    for (int o = 1; o < 256; o <<= 1) {
        int a = (t >= o) ? part[t - o] : 0; __syncthreads();
        part[t] += a; __syncthreads();
    }
    int bs = part[t] - ps;
    off[2 * t] = bs;          cur[2 * t] = bs;
    off[2 * t + 1] = bs + c0; cur[2 * t + 1] = bs + c0;
    if (t == 255) totE = part[255];
    __syncthreads();
    // bucket-sorted scatter into LDS (both entries per edge)
    #pragma unroll
    for (int j = 0; j < 8; j++) {
        if (bA[j] >= 0) {
            int p = atomicAdd(&cur[(int)bA[j]], 1);
            sortedL[p] = eA[j]; bktL[p] = (unsigned short)bA[j];
            p = atomicAdd(&cur[(int)bB[j]], 1);
            sortedL[p] = eB[j]; bktL[p] = (unsigned short)bB[j];
        }
    }
    __syncthreads();
    // reserve global slab space, one atomic per non-empty bucket
    for (int b = t; b < 512; b += 256) {
        int n = cnt[b];
        if (n > 0) gbase[b] = atomicAdd(&gCur[b], n);
    }
    __syncthreads();
    int nE = totE;
    for (int i = t; i < nE; i += 256) {
        int b = bktL[i];
        slab[slabBase[b] + gbase[b] + (i - off[b])] = sortedL[i];
    }
}

// ---------- phase B (per direction): slab bucket -> padded per-row table ----------
// srt row dd: KPAD uint2 slots; slot0.x bits 27-31 = min(count,31); overflow -> ovf.
__global__ __launch_bounds__(512) void phaseB_pad(const uint2* __restrict__ slab,
                                                  const int* __restrict__ slabBase,
                                                  int bucketBase,
                                                  uint2* __restrict__ srt,
                                                  int* __restrict__ ovfCnt,
                                                  uint4* __restrict__ ovf) {
    __shared__ int cur[DPB];
    int t = threadIdx.x;
    int b = blockIdx.x + bucketBase;
    int s0 = slabBase[b], se = slabBase[b + 1];
    int n = se - s0;
    for (int d = t; d < DPB; d += 512) cur[d] = 0;
    __syncthreads();
    int destBase = blockIdx.x * DPB;
    for (int i = t; i < n; i += 512) {
        uint2 e = slab[s0 + i];
        int dl = e.x >> 18;
        int p = atomicAdd(&cur[dl], 1);
        if (p < KPAD) {
            srt[(size_t)(destBase + dl) * KPAD + p] = make_uint2(e.x & 0x3FFFFu, e.y);
        } else {
            int o = atomicAdd(ovfCnt, 1);
            if (o < OVF_CAP) ovf[o] = make_uint4((unsigned)(destBase + dl),
                                                 e.x & 0x3FFFFu, e.y, 0u);
        }
    }
    __syncthreads();     // drains vmcnt -> scatter stores are in L2 before fixup
    for (int d = t; d < DPB; d += 512) {
        int dd = destBase + d;
        int c = cur[d];
        size_t p0 = (size_t)dd * KPAD;
        if (c == 0) {
            srt[p0] = make_uint2(0u, 0u);            // stale row -> nenc=0
        } else {
            unsigned nenc = (unsigned)(c > 31 ? 31 : c) << 27;
            __hip_atomic_fetch_or((unsigned*)&srt[p0].x, nenc,
                                  __ATOMIC_RELAXED, __HIP_MEMORY_SCOPE_AGENT);
        }
    }
}

// ---------- gather 1: one s_load batch per row (no dependent chain) ----------
__global__ __launch_bounds__(256) void gather1(const uint* __restrict__ srcBf,
                                               const uint2* __restrict__ srt,
                                               const int* __restrict__ ovfCnt,
                                               const uint4* __restrict__ ovf,
                                               uint* __restrict__ dstBf) {
    int lane = threadIdx.x & 63;
    int row = blockIdx.x * 4 + (threadIdx.x >> 6);      // grid covers exactly N_TOTAL
    int row_u = __builtin_amdgcn_readfirstlane(row);
    uvec16 mA, mB; uvec8 mC;
    sload_row(mA, mB, mC, srt + (size_t)row_u * KPAD);
    int n = (int)(mA[0] >> 27);
    float ax = 0.f, ay = 0.f, bx = 0.f, by = 0.f;
    chunk8(mA, n < 8 ? n : 8, lane, srcBf, ax, ay, bx, by);
    if (n > 8) {
        chunk8(mB, n - 8 < 8 ? n - 8 : 8, lane, srcBf, ax, ay, bx, by);
        if (n > 16) {
            chunk4(mC, n - 16 < 4 ? n - 16 : 4, lane, srcBf, ax, ay, bx, by);
            if (n > KPAD) {                             // rare: ~0.16% of rows
                int oc = *ovfCnt; oc = oc < OVF_CAP ? oc : OVF_CAP;
                for (int i = 0; i < oc; i++) {
                    uint4 e = ovf[i];
                    if (e.x == (unsigned)row_u) {
                        float v = __uint_as_float(e.z);
                        float2 u = unpack_bf16(srcBf[(((size_t)e.y) << 6) + lane]);
                        ax += v * u.x; ay += v * u.y;
                    }
                }
            }
        }
    }
    dstBf[(size_t)row_u * 64 + lane] = pack_bf16(ax + bx, ay + by);
}

// ---------- gather 2 + LN + residual ----------
__global__ __launch_bounds__(256) void gather2_ln(const uint* __restrict__ hBf,
                                                  const uint2* __restrict__ srt,
                                                  const int* __restrict__ ovfCnt,
                                                  const uint4* __restrict__ ovf,
                                                  const uint* __restrict__ egoBf,
                                                  const float* __restrict__ gamma,
                                                  const float* __restrict__ beta,
                                                  float* __restrict__ out) {
    int lane = threadIdx.x & 63;
    int row = blockIdx.x * 4 + (threadIdx.x >> 6);
    int row_u = __builtin_amdgcn_readfirstlane(row);
    uvec16 mA, mB; uvec8 mC;
    sload_row(mA, mB, mC, srt + (size_t)row_u * KPAD);
    int n = (int)(mA[0] >> 27);
    float ax = 0.f, ay = 0.f, bx = 0.f, by = 0.f;
    chunk8(mA, n < 8 ? n : 8, lane, hBf, ax, ay, bx, by);
    if (n > 8) {
        chunk8(mB, n - 8 < 8 ? n - 8 : 8, lane, hBf, ax, ay, bx, by);
        if (n > 16) {
            chunk4(mC, n - 16 < 4 ? n - 16 : 4, lane, hBf, ax, ay, bx, by);
            if (n > KPAD) {
                int oc = *ovfCnt; oc = oc < OVF_CAP ? oc : OVF_CAP;
                for (int i = 0; i < oc; i++) {
                    uint4 e = ovf[i];
                    if (e.x == (unsigned)row_u) {
                        float v = __uint_as_float(e.z);
                        float2 u = unpack_bf16(hBf[(((size_t)e.y) << 6) + lane]);
                        ax += v * u.x; ay += v * u.y;
                    }
                }
            }
        }
    }
    float2 acc = make_float2(ax + bx, ay + by);
    float s = acc.x + acc.y;
    float sq = acc.x * acc.x + acc.y * acc.y;
    #pragma unroll
    for (int o = 1; o <= 16; o <<= 1) {
        s  += __shfl_xor(s, o, 64);
        sq += __shfl_xor(sq, o, 64);
    }
    float sT  = rdlane_f(s, 0)  + rdlane_f(s, 32);
    float sqT = rdlane_f(sq, 0) + rdlane_f(sq, 32);
    float mu = sT * (1.0f / DIM);
    float var = sqT * (1.0f / DIM) - mu * mu;
    float rs = rsqrtf(var + 1e-5f);
    float2 g  = ((const float2*)gamma)[lane];
    float2 bb = ((const float2*)beta)[lane];
    unsigned egoW = __builtin_nontemporal_load(&egoBf[(size_t)row_u * 64 + lane]);
    float2 e2 = unpack_bf16(egoW);
    float2 o2;
    o2.x = (acc.x - mu) * rs * g.x + bb.x + e2.x;
    o2.y = (acc.y - mu) * rs * g.y + bb.y + e2.y;
    u64 ow = (u64)__float_as_uint(o2.x) | ((u64)__float_as_uint(o2.y) << 32);
    __builtin_nontemporal_store(ow, (u64*)out + (size_t)row_u * 64 + lane);
}

// ---------- fallback: atomic scatter path (ws too small) ----------
__device__ __forceinline__ void atomic_add_f32(float* p, float v) {
    __hip_atomic_fetch_add(p, v, __ATOMIC_RELAXED, __HIP_MEMORY_SCOPE_AGENT);
}
__global__ void scatter_kernel(const float* __restrict__ src, const float* __restrict__ vals,
                               const int* __restrict__ gidx, const int* __restrict__ sidx,
                               float* __restrict__ dst, int nnz) {
    int gid = blockIdx.x * blockDim.x + threadIdx.x;
    int e = gid >> 5, lane = gid & 31;
    if (e >= nnz) return;
    float v = vals[e];
    float4 x = ((const float4*)(src + (size_t)gidx[e] * DIM))[lane];
    float* d = dst + (size_t)sidx[e] * DIM + lane * 4;
    atomic_add_f32(d + 0, v * x.x); atomic_add_f32(d + 1, v * x.y);
    atomic_add_f32(d + 2, v * x.z); atomic_add_f32(d + 3, v * x.w);
}
__global__ void ln_residual_kernel(const float* __restrict__ h2, const float* __restrict__ ego,
                                   const float* __restrict__ gamma, const float* __restrict__ beta,
                                   float* __restrict__ out, int nrows) {
    int gid = blockIdx.x * blockDim.x + threadIdx.x;
    int row = gid >> 6, lane = gid & 63;
    if (row >= nrows) return;
    float2 x = ((const float2*)(h2 + (size_t)row * DIM))[lane];
    float s = x.x + x.y, sq = x.x * x.x + x.y * x.y;
    #pragma unroll
    for (int o = 32; o > 0; o >>= 1) { s += __shfl_xor(s, o, 64); sq += __shfl_xor(sq, o, 64); }
    float mu = s * (1.0f / DIM), var = sq * (1.0f / DIM) - mu * mu;
    float rs = rsqrtf(var + 1e-5f);
    float2 eg = ((const float2*)(ego + (size_t)row * DIM))[lane];
    float2 g = ((const float2*)gamma)[lane], b = ((const float2*)beta)[lane];
    float2 o2;
    o2.x = (x.x - mu) * rs * g.x + b.x + eg.x;
    o2.y = (x.y - mu) * rs * g.y + b.y + eg.y;
    ((float2*)(out + (size_t)row * DIM))[lane] = o2;
}

// ---------- launch ----------
extern "C" void kernel_launch(void* const* d_in, const int* in_sizes, int n_in,
                              void* d_out, int out_size, void* d_ws, size_t ws_size,
                              hipStream_t stream) {
    (void)out_size;   // semantics unverified (round-7 lesson); geometry is compile-time fixed
    const float* ego   = (const float*)d_in[0];
    const float* vals  = (const float*)d_in[1];
    const float* gamma = (const float*)d_in[2];
    const float* beta  = (const float*)d_in[3];
    const int*   rows  = (const int*)d_in[4];
    const int*   cols  = (const int*)d_in[5];
    float* out = (float*)d_out;

    const size_t EGO_BF_B = (size_t)N_TOTAL * DIM * 2;               // 38.4 MB
    const size_t H_BF_B   = (size_t)N_TOTAL * DIM * 2;               // 38.4 MB
    const size_t SRT_B    = (size_t)N_PAD * KPAD * sizeof(uint2);    // 24.0 MB
    const size_t OVF_B    = (size_t)OVF_CAP * 16;                    // 128 KB each
    const size_t REQ = EGO_BF_B + H_BF_B + SRT_B + 8192 + 2 * OVF_B; // ~101.1 MB
    const size_t H_FP32_B = (size_t)N_TOTAL * DIM * sizeof(float);   // fallback: 76.8 MB

    char* w = (char*)d_ws;
    uint* egoBf   = (uint*)w;   w += EGO_BF_B;
    uint* hBf     = (uint*)w;   w += H_BF_B;
    uint2* srt    = (uint2*)w;  w += SRT_B;
    int* cntArr   = (int*)w;    w += 512 * sizeof(int);
    int* ovfc     = (int*)w;    w += 64 * sizeof(int);   // [0]=dir1, [32]=dir2
    int* sb       = (int*)w;    w += 516 * sizeof(int);
    int* gc       = (int*)w;    w += 512 * sizeof(int);
    uint4* ovf1   = (uint4*)w;  w += OVF_B;
    uint4* ovf2   = (uint4*)w;  w += OVF_B;
    uint2* slab   = (uint2*)d_out;       // 24 MB scratch in the 76.8 MB output buffer;
                                         // dead before gather2_ln writes out

    if (ws_size >= REQ) {
        (void)hipMemsetAsync(cntArr, 0, (512 + 64) * sizeof(int), stream);
        conv_hist<<<CONV_BLOCKS + HIST_BLOCKS, 256, 0, stream>>>(ego, egoBf, rows, cols,
                                                                 cntArr, cntArr + 256);
        scan_buckets<<<1, 256, 0, stream>>>(cntArr, sb, gc);
        phaseA_fused<<<A2_BLOCKS, 256, 0, stream>>>(rows, cols, vals, sb, gc, slab);

        int ggrid = (N_TOTAL + 3) / 4;      // 4 waves/block, 1 row/wave -> 37500
        phaseB_pad<<<NBUCK, 512, 0, stream>>>(slab, sb, 0, srt, ovfc, ovf1);
        gather1<<<ggrid, 256, 0, stream>>>(egoBf, srt, ovfc, ovf1, hBf);
        phaseB_pad<<<NBUCK, 512, 0, stream>>>(slab, sb, 256, srt, ovfc + 32, ovf2);
        gather2_ln<<<ggrid, 256, 0, stream>>>(hBf, srt, ovfc + 32, ovf2,
                                              egoBf, gamma, beta, out);
    } else {
        float* h = (float*)d_ws;            // fallback: fp32 h at ws start
        (void)hipMemsetAsync(h, 0, H_FP32_B, stream);
        (void)hipMemsetAsync(out, 0, H_FP32_B, stream);
        long total = (long)NNZ_E * 32;
        int grid = (int)((total + 255) / 256);
        scatter_kernel<<<grid, 256, 0, stream>>>(ego, vals, rows, cols, h, NNZ_E);
        scatter_kernel<<<grid, 256, 0, stream>>>(h, vals, cols, rows, out, NNZ_E);
        int lngrid = (N_TOTAL * 64 + 255) / 256;
        ln_residual_kernel<<<lngrid, 256, 0, stream>>>(out, ego, gamma, beta, out, N_TOTAL);
    }
}

// Round 9
// 354.950 us; speedup vs baseline: 14.5498x; 1.1981x over previous
//
#include <hip/hip_runtime.h>

#define N_TOTAL 150000
#define DIM 128
#define NNZ_E 1500000
#define NBUCK 256
#define DPB 586                 // dests per bucket: 256*586 = 150016 >= 150000
#define EPB2 2048               // edges per fused phase-A block (emits 2 entries each)
#define A2_BLOCKS ((NNZ_E + EPB2 - 1) / EPB2)   // 733
#define CONV_BLOCKS 9375        // N_TOTAL*DIM/8 / 256
#define HIST_BLOCKS 512

typedef unsigned long long u64;
typedef unsigned uvec16 __attribute__((ext_vector_type(16)));
typedef unsigned uvec2  __attribute__((ext_vector_type(2)));

// ---------- bf16 pack/unpack (RNE) ----------
__device__ __forceinline__ unsigned pack_bf16_bits(unsigned ua, unsigned ub) {
    ua = (ua + 0x7FFFu + ((ua >> 16) & 1u)) >> 16;
    ub = (ub + 0x7FFFu + ((ub >> 16) & 1u)) >> 16;
    return ua | (ub << 16);
}
__device__ __forceinline__ unsigned pack_bf16(float a, float b) {
    return pack_bf16_bits(__float_as_uint(a), __float_as_uint(b));
}
__device__ __forceinline__ float2 unpack_bf16(unsigned u) {
    return make_float2(__uint_as_float(u << 16), __uint_as_float(u & 0xFFFF0000u));
}
__device__ __forceinline__ float rdlane_f(float x, int l) {
    return __uint_as_float((unsigned)__builtin_amdgcn_readlane((int)__float_as_uint(x), l));
}

// ---------- scalar-pipe metadata loads (wave-uniform) ----------
__device__ __forceinline__ void sload_pair(uvec16 &a, uvec16 &b, const void* p) {
    asm volatile("s_load_dwordx16 %0, %2, 0x0\n\t"
                 "s_load_dwordx16 %1, %2, 0x40\n\t"
                 "s_waitcnt lgkmcnt(0)"
                 : "=&s"(a), "=&s"(b) : "s"(p) : "memory");
}
__device__ __forceinline__ void sload_be(uvec2 &r, const void* p) {
    asm volatile("s_load_dwordx2 %0, %1, 0x0\n\t"
                 "s_waitcnt lgkmcnt(0)"
                 : "=&s"(r) : "s"(p) : "memory");
}

// process 8 edges from an SGPR chunk; lim = valid count (scalar).
// Speculative slots: index AND weight gated scalar-side (s_cselect) -> invalid
// slots load row 0 (L1-hot). Loads stay branchless -> batch issues in parallel.
__device__ __forceinline__ void chunk8(const uvec16 &m, int lim, int lane,
                                       const uint* __restrict__ srcBf,
                                       float &ax, float &ay, float &bx, float &by) {
    #pragma unroll
    for (int j = 0; j < 8; j++) {
        unsigned sx = (j < lim) ? (m[2 * j] & 0x3FFFFu) : 0u;
        float vv = (j < lim) ? __uint_as_float(m[2 * j + 1]) : 0.0f;
        const uint* p = srcBf + ((size_t)sx << 6);   // uniform base -> saddr load
        float2 uu = unpack_bf16(p[lane]);
        if (j & 1) { bx += vv * uu.x; by += vv * uu.y; }
        else       { ax += vv * uu.x; ay += vv * uu.y; }
    }
}

// ---------- fused: ego fp32 -> bf16 (blocks < CONV_BLOCKS) || coarse hist ----------
__global__ __launch_bounds__(256) void conv_hist(const float* __restrict__ in,
                                                 uint* __restrict__ outp,
                                                 const int* __restrict__ rows,
                                                 const int* __restrict__ cols,
                                                 int* __restrict__ cnt1,
                                                 int* __restrict__ cnt2) {
    __shared__ int h[512];
    int t = threadIdx.x;
    if (blockIdx.x < CONV_BLOCKS) {
        int i = blockIdx.x * 256 + t;                // exactly N*D/8 threads
        const u64* in8 = (const u64*)in;
        u64 w0 = __builtin_nontemporal_load(&in8[4 * i + 0]);
        u64 w1 = __builtin_nontemporal_load(&in8[4 * i + 1]);
        u64 w2 = __builtin_nontemporal_load(&in8[4 * i + 2]);
        u64 w3 = __builtin_nontemporal_load(&in8[4 * i + 3]);
        uint4 o;
        o.x = pack_bf16_bits((unsigned)w0, (unsigned)(w0 >> 32));
        o.y = pack_bf16_bits((unsigned)w1, (unsigned)(w1 >> 32));
        o.z = pack_bf16_bits((unsigned)w2, (unsigned)(w2 >> 32));
        o.w = pack_bf16_bits((unsigned)w3, (unsigned)(w3 >> 32));
        ((uint4*)outp)[i] = o;
    } else {
        h[t] = 0; h[t + 256] = 0;
        __syncthreads();
        int bid = blockIdx.x - CONV_BLOCKS;
        int stride = HIST_BLOCKS * 256;
        for (int e = bid * 256 + t; e < NNZ_E; e += stride) {
            atomicAdd(&h[cols[e] / DPB], 1);          // pass-1 dest = col
            atomicAdd(&h[256 + rows[e] / DPB], 1);    // pass-2 dest = row
        }
        __syncthreads();
        if (h[t]) atomicAdd(&cnt1[t], h[t]);
        if (h[t + 256]) atomicAdd(&cnt2[t], h[t + 256]);
    }
}

// ---------- fused phase A: inline bucket scan + bin 2048 edges -> slab ----------
__global__ __launch_bounds__(256) void phaseA_fused(const int* __restrict__ rows,
                                                    const int* __restrict__ cols,
                                                    const float* __restrict__ vals,
                                                    const int* __restrict__ gcnt,
                                                    int* __restrict__ gCur,
                                                    int* __restrict__ sbG,
                                                    uint2* __restrict__ slab) {
    __shared__ uint2 sortedL[2 * EPB2];          // 32 KB
    __shared__ unsigned short bktL[2 * EPB2];    // 8 KB
    __shared__ int cnt[512], off[512], cur[512], gbase[512];   // 8 KB
    __shared__ int part[256];                    // 1 KB
    __shared__ int sbL[513];                     // 2 KB: bucket bases (computed here)
    __shared__ int totE;
    int t = threadIdx.x;
    int base = blockIdx.x * EPB2;
    cnt[t] = 0; cnt[t + 256] = 0;

    // ---- inline scan of global hist counts -> sbL (replaces scan_buckets) ----
    int g0 = gcnt[t];
    part[t] = g0; __syncthreads();
    for (int o = 1; o < 256; o <<= 1) {
        int a = (t >= o) ? part[t - o] : 0; __syncthreads();
        part[t] += a; __syncthreads();
    }
    sbL[t] = part[t] - g0;                   // dir-1 region: [0, NNZ)
    __syncthreads();
    int g1 = gcnt[256 + t];
    part[t] = g1; __syncthreads();
    for (int o = 1; o < 256; o <<= 1) {
        int a = (t >= o) ? part[t - o] : 0; __syncthreads();
        part[t] += a; __syncthreads();
    }
    sbL[256 + t] = NNZ_E + part[t] - g1;     // dir-2 region: [NNZ, 2*NNZ)
    if (t == 0) sbL[512] = 2 * NNZ_E;
    if (blockIdx.x == 0) {                   // publish for phaseB
        sbG[t] = sbL[t]; sbG[256 + t] = sbL[256 + t];
        if (t == 0) sbG[512] = 2 * NNZ_E;
    }
    __syncthreads();

    uint2 eA[8], eB[8];
    short bA[8], bB[8];
    #pragma unroll
    for (int j = 0; j < 8; j++) {
        int e = base + j * 256 + t;
        if (e < NNZ_E) {
            int r = rows[e], c = cols[e];
            unsigned v = __float_as_uint(vals[e]);
            int b1 = c / DPB, dl1 = c - b1 * DPB;     // pass-1 dest = col, src = row
            int b2 = r / DPB, dl2 = r - b2 * DPB;     // pass-2 dest = row, src = col
            bA[j] = (short)b1;
            eA[j].x = ((unsigned)dl1 << 18) | (unsigned)r;
            eA[j].y = v;
            bB[j] = (short)(256 + b2);
            eB[j].x = ((unsigned)dl2 << 18) | (unsigned)c;
            eB[j].y = v;
            atomicAdd(&cnt[b1], 1);
            atomicAdd(&cnt[256 + b2], 1);
        } else { bA[j] = -1; bB[j] = -1; }
    }
    __syncthreads();
    // scan 512 counts (2 per thread) -> exclusive off/cur
    int c0 = cnt[2 * t], c1 = cnt[2 * t + 1];
    int ps = c0 + c1;
    part[t] = ps; __syncthreads();
    for (int o = 1; o < 256; o <<= 1) {
        int a = (t >= o) ? part[t - o] : 0; __syncthreads();
        part[t] += a; __syncthreads();
    }
    int bs = part[t] - ps;
    off[2 * t] = bs;          cur[2 * t] = bs;
    off[2 * t + 1] = bs + c0; cur[2 * t + 1] = bs + c0;
    if (t == 255) totE = part[255];
    __syncthreads();
    // bucket-sorted scatter into LDS (both entries per edge)
    #pragma unroll
    for (int j = 0; j < 8; j++) {
        if (bA[j] >= 0) {
            int p = atomicAdd(&cur[(int)bA[j]], 1);
            sortedL[p] = eA[j]; bktL[p] = (unsigned short)bA[j];
            p = atomicAdd(&cur[(int)bB[j]], 1);
            sortedL[p] = eB[j]; bktL[p] = (unsigned short)bB[j];
        }
    }
    __syncthreads();
    // reserve global slab space, one atomic per non-empty bucket
    for (int b = t; b < 512; b += 256) {
        int n = cnt[b];
        if (n > 0) gbase[b] = atomicAdd(&gCur[b], n);
    }
    __syncthreads();
    int nE = totE;
    for (int i = t; i < nE; i += 256) {
        int b = bktL[i];
        slab[sbL[b] + gbase[b] + (i - off[b])] = sortedL[i];
    }
}

// ---------- phase B: per-bucket exact sort + offs write + (src,val) emit ----------
__global__ __launch_bounds__(256) void phaseB(const uint2* __restrict__ slab,
                                              const int* __restrict__ slabBase,
                                              int* __restrict__ offs1,
                                              int* __restrict__ offs2,
                                              uint2* __restrict__ sorted) {
    __shared__ int cnt[DPB], sc[DPB], cur[DPB], part[256];
    int b = blockIdx.x, t = threadIdx.x;
    int sb = slabBase[b], se = slabBase[b + 1];
    int n = se - sb;
    for (int d = t; d < DPB; d += 256) cnt[d] = 0;
    __syncthreads();
    for (int i = t; i < n; i += 256)
        atomicAdd(&cnt[slab[sb + i].x >> 18], 1);
    __syncthreads();
    int d0 = t * 3;
    int c0 = (d0     < DPB) ? cnt[d0]     : 0;
    int c1 = (d0 + 1 < DPB) ? cnt[d0 + 1] : 0;
    int c2 = (d0 + 2 < DPB) ? cnt[d0 + 2] : 0;
    int ps = c0 + c1 + c2;
    part[t] = ps;
    __syncthreads();
    for (int o = 1; o < 256; o <<= 1) {
        int a = (t >= o) ? part[t - o] : 0; __syncthreads();
        part[t] += a; __syncthreads();
    }
    int bs = part[t] - ps;
    if (d0     < DPB) { sc[d0]     = bs;           cur[d0]     = bs; }
    if (d0 + 1 < DPB) { sc[d0 + 1] = bs + c0;      cur[d0 + 1] = bs + c0; }
    if (d0 + 2 < DPB) { sc[d0 + 2] = bs + c0 + c1; cur[d0 + 2] = bs + c0 + c1; }
    __syncthreads();
    int destBase = (b & 255) * DPB;
    int* offs = (b < NBUCK) ? offs1 : offs2;
    for (int d = t; d < DPB; d += 256) {
        int dd = destBase + d;
        if (dd <= N_TOTAL) offs[dd] = sb + sc[d];   // absolute index into sorted[]
    }
    for (int i = t; i < n; i += 256) {
        uint2 e = slab[sb + i];
        int dl = e.x >> 18;
        int p = atomicAdd(&cur[dl], 1);
        sorted[sb + p] = make_uint2(e.x & 0x3FFFF, e.y);
    }
}

// ---------- gather 1: SGPR metadata, saddr gathers, bf16 in/out ----------
__global__ __launch_bounds__(256) void gather1(const uint* __restrict__ srcBf,
                                               const int* __restrict__ offs,
                                               const uint2* __restrict__ edges,
                                               uint* __restrict__ dstBf) {
    int lane = threadIdx.x & 63;
    int row = blockIdx.x * 4 + (threadIdx.x >> 6);      // grid covers exactly N_TOTAL
    int row_u = __builtin_amdgcn_readfirstlane(row);
    uvec2 be;
    sload_be(be, offs + row_u);
    int beg = (int)be[0];
    int n = (int)be[1] - beg;
    const u64* ep = (const u64*)edges + beg;
    uvec16 mA, mB;
    sload_pair(mA, mB, ep);                             // <=128B past array end stays in ws
    float ax = 0.f, ay = 0.f, bx = 0.f, by = 0.f;
    chunk8(mA, n < 8 ? n : 8, lane, srcBf, ax, ay, bx, by);
    if (n > 8) {
        chunk8(mB, n - 8 < 8 ? n - 8 : 8, lane, srcBf, ax, ay, bx, by);
        if (n > 16) {
            uvec16 mC, mD;
            sload_pair(mC, mD, ep + 16);
            chunk8(mC, n - 16 < 8 ? n - 16 : 8, lane, srcBf, ax, ay, bx, by);
            if (n > 24) {
                chunk8(mD, n - 24 < 8 ? n - 24 : 8, lane, srcBf, ax, ay, bx, by);
                for (int k = 32; k < n; k++) {          // statistically never
                    uint2 e = edges[beg + k];
                    float v = __uint_as_float(e.y);
                    float2 u = unpack_bf16(srcBf[(((size_t)e.x) << 6) + lane]);
                    ax += v * u.x; ay += v * u.y;
                }
            }
        }
    }
    dstBf[(size_t)row_u * 64 + lane] = pack_bf16(ax + bx, ay + by);
}

// ---------- gather 2 + LN + residual: SGPR metadata, saddr gathers ----------
__global__ __launch_bounds__(256) void gather2_ln(const uint* __restrict__ hBf,
                                                  const int* __restrict__ offs,
                                                  const uint2* __restrict__ edges,
                                                  const uint* __restrict__ egoBf,
                                                  const float* __restrict__ gamma,
                                                  const float* __restrict__ beta,
                                                  float* __restrict__ out) {
    int lane = threadIdx.x & 63;
    int row = blockIdx.x * 4 + (threadIdx.x >> 6);
    int row_u = __builtin_amdgcn_readfirstlane(row);
    uvec2 be;
    sload_be(be, offs + row_u);
    int beg = (int)be[0];
    int n = (int)be[1] - beg;
    const u64* ep = (const u64*)edges + beg;
    uvec16 mA, mB;
    sload_pair(mA, mB, ep);
    float ax = 0.f, ay = 0.f, bx = 0.f, by = 0.f;
    chunk8(mA, n < 8 ? n : 8, lane, hBf, ax, ay, bx, by);
    if (n > 8) {
        chunk8(mB, n - 8 < 8 ? n - 8 : 8, lane, hBf, ax, ay, bx, by);
        if (n > 16) {
            uvec16 mC, mD;
            sload_pair(mC, mD, ep + 16);
            chunk8(mC, n - 16 < 8 ? n - 16 : 8, lane, hBf, ax, ay, bx, by);
            if (n > 24) {
                chunk8(mD, n - 24 < 8 ? n - 24 : 8, lane, hBf, ax, ay, bx, by);
                for (int k = 32; k < n; k++) {
                    uint2 e = edges[beg + k];
                    float v = __uint_as_float(e.y);
                    float2 u = unpack_bf16(hBf[(((size_t)e.x) << 6) + lane]);
                    ax += v * u.x; ay += v * u.y;
                }
            }
        }
    }
    float2 acc = make_float2(ax + bx, ay + by);
    float s = acc.x + acc.y;
    float sq = acc.x * acc.x + acc.y * acc.y;
    #pragma unroll
    for (int o = 1; o <= 16; o <<= 1) {
        s  += __shfl_xor(s, o, 64);
        sq += __shfl_xor(sq, o, 64);
    }
    // lanes 0 and 32 hold the two half-sums -> finish with scalar readlanes
    float sT  = rdlane_f(s, 0)  + rdlane_f(s, 32);
    float sqT = rdlane_f(sq, 0) + rdlane_f(sq, 32);
    float mu = sT * (1.0f / DIM);
    float var = sqT * (1.0f / DIM) - mu * mu;
    float rs = rsqrtf(var + 1e-5f);
    float2 g  = ((const float2*)gamma)[lane];
    float2 bb = ((const float2*)beta)[lane];
    unsigned egoW = __builtin_nontemporal_load(&egoBf[(size_t)row_u * 64 + lane]);
    float2 e2 = unpack_bf16(egoW);
    float2 o2;
    o2.x = (acc.x - mu) * rs * g.x + bb.x + e2.x;
    o2.y = (acc.y - mu) * rs * g.y + bb.y + e2.y;
    u64 ow = (u64)__float_as_uint(o2.x) | ((u64)__float_as_uint(o2.y) << 32);
    __builtin_nontemporal_store(ow, (u64*)out + (size_t)row_u * 64 + lane);
}

// ---------- fallback: atomic scatter path (ws too small) ----------
__device__ __forceinline__ void atomic_add_f32(float* p, float v) {
    __hip_atomic_fetch_add(p, v, __ATOMIC_RELAXED, __HIP_MEMORY_SCOPE_AGENT);
}
__global__ void scatter_kernel(const float* __restrict__ src, const float* __restrict__ vals,
                               const int* __restrict__ gidx, const int* __restrict__ sidx,
                               float* __restrict__ dst, int nnz) {
    int gid = blockIdx.x * blockDim.x + threadIdx.x;
    int e = gid >> 5, lane = gid & 31;
    if (e >= nnz) return;
    float v = vals[e];
    float4 x = ((const float4*)(src + (size_t)gidx[e] * DIM))[lane];
    float* d = dst + (size_t)sidx[e] * DIM + lane * 4;
    atomic_add_f32(d + 0, v * x.x); atomic_add_f32(d + 1, v * x.y);
    atomic_add_f32(d + 2, v * x.z); atomic_add_f32(d + 3, v * x.w);
}
__global__ void ln_residual_kernel(const float* __restrict__ h2, const float* __restrict__ ego,
                                   const float* __restrict__ gamma, const float* __restrict__ beta,
                                   float* __restrict__ out, int nrows) {
    int gid = blockIdx.x * blockDim.x + threadIdx.x;
    int row = gid >> 6, lane = gid & 63;
    if (row >= nrows) return;
    float2 x = ((const float2*)(h2 + (size_t)row * DIM))[lane];
    float s = x.x + x.y, sq = x.x * x.x + x.y * x.y;
    #pragma unroll
    for (int o = 32; o > 0; o >>= 1) { s += __shfl_xor(s, o, 64); sq += __shfl_xor(sq, o, 64); }
    float mu = s * (1.0f / DIM), var = sq * (1.0f / DIM) - mu * mu;
    float rs = rsqrtf(var + 1e-5f);
    float2 eg = ((const float2*)(ego + (size_t)row * DIM))[lane];
    float2 g = ((const float2*)gamma)[lane], b = ((const float2*)beta)[lane];
    float2 o2;
    o2.x = (x.x - mu) * rs * g.x + b.x + eg.x;
    o2.y = (x.y - mu) * rs * g.y + b.y + eg.y;
    ((float2*)(out + (size_t)row * DIM))[lane] = o2;
}

// ---------- launch ----------
extern "C" void kernel_launch(void* const* d_in, const int* in_sizes, int n_in,
                              void* d_out, int out_size, void* d_ws, size_t ws_size,
                              hipStream_t stream) {
    const float* ego   = (const float*)d_in[0];
    const float* vals  = (const float*)d_in[1];
    const float* gamma = (const float*)d_in[2];
    const float* beta  = (const float*)d_in[3];
    const int*   rows  = (const int*)d_in[4];
    const int*   cols  = (const int*)d_in[5];
    float* out = (float*)d_out;

    const size_t EGO_BF_B = (size_t)N_TOTAL * DIM * 2;               // 38.4 MB
    const size_t SLAB_B   = (size_t)2 * NNZ_E * sizeof(uint2);       // 24 MB
    const size_t H_BF_B   = (size_t)N_TOTAL * DIM * 2;               // 38.4 MB
    const size_t REGION_B = (SLAB_B > H_BF_B) ? SLAB_B : H_BF_B;     // hBf aliases dead slab
    const size_t SORT_B   = (size_t)2 * NNZ_E * sizeof(uint2);       // 24 MB
    const size_t OFFS_B   = ((size_t)N_TOTAL + 16) * sizeof(int);    // ~0.6 MB each
    const size_t SMALL    = 16384;
    const size_t REQ = EGO_BF_B + REGION_B + SORT_B + 2 * OFFS_B + SMALL;   // ~102 MB
    const size_t H_FP32_B = (size_t)N_TOTAL * DIM * sizeof(float);   // fallback: 76.8 MB

    char* w = (char*)d_ws;
    uint* egoBf   = (uint*)w;   w += EGO_BF_B;
    char* region  = w;          w += REGION_B;
    uint2* slab   = (uint2*)region;      // live: phaseA_fused -> phaseB
    uint* hBf     = (uint*)region;       // live: gather1 -> gather2 (slab dead by then)
    uint2* sorted = (uint2*)w;  w += SORT_B;
    int* offs1    = (int*)w;    w += OFFS_B;
    int* offs2    = (int*)w;    w += OFFS_B;
    int* cntArr   = (int*)w;    w += 512 * sizeof(int);   // cntArr + gc contiguous: one memset
    int* gc       = (int*)w;    w += 512 * sizeof(int);
    int* sb       = (int*)w;    w += 516 * sizeof(int);

    if (ws_size >= REQ) {
        (void)hipMemsetAsync(cntArr, 0, 1024 * sizeof(int), stream);
        conv_hist<<<CONV_BLOCKS + HIST_BLOCKS, 256, 0, stream>>>(ego, egoBf, rows, cols,
                                                                 cntArr, cntArr + 256);
        phaseA_fused<<<A2_BLOCKS, 256, 0, stream>>>(rows, cols, vals, cntArr, gc, sb, slab);
        phaseB<<<512, 256, 0, stream>>>(slab, sb, offs1, offs2, sorted);

        int ggrid = (N_TOTAL + 3) / 4;      // 4 waves/block, 1 row/wave -> 37500
        gather1<<<ggrid, 256, 0, stream>>>(egoBf, offs1, sorted, hBf);
        gather2_ln<<<ggrid, 256, 0, stream>>>(hBf, offs2, sorted, egoBf, gamma, beta, out);
    } else {
        float* h = (float*)d_ws;            // fallback: fp32 h at ws start
        (void)hipMemsetAsync(h, 0, H_FP32_B, stream);
        (void)hipMemsetAsync(out, 0, H_FP32_B, stream);
        long total = (long)NNZ_E * 32;
        int grid = (int)((total + 255) / 256);
        scatter_kernel<<<grid, 256, 0, stream>>>(ego, vals, rows, cols, h, NNZ_E);
        scatter_kernel<<<grid, 256, 0, stream>>>(h, vals, cols, rows, out, NNZ_E);
        int lngrid = (N_TOTAL * 64 + 255) / 256;
        ln_residual_kernel<<<lngrid, 256, 0, stream>>>(out, ego, gamma, beta, out, N_TOTAL);
    }
}

// Round 10
// 338.745 us; speedup vs baseline: 15.2459x; 1.0478x over previous
//
#include <hip/hip_runtime.h>

#define N_TOTAL 150000
#define DIM 128
#define NNZ_E 1500000
#define NBUCK 256
#define DPB 586                 // dests per bucket: 256*586 = 150016 >= 150000
#define EPB2 2048               // edges per fused phase-A block (emits 2 entries each)
#define A2_BLOCKS ((NNZ_E + EPB2 - 1) / EPB2)   // 733
#define CONV_BLOCKS 9375        // N_TOTAL*DIM/8 / 256
#define HIST_BLOCKS 512
#define MAXE 16                 // phaseB register slots/thread: 512*16=8192 >= max bucket n

typedef unsigned long long u64;
typedef unsigned uvec16 __attribute__((ext_vector_type(16)));
typedef unsigned uvec2  __attribute__((ext_vector_type(2)));

// ---------- bf16 pack/unpack (RNE) ----------
__device__ __forceinline__ unsigned pack_bf16_bits(unsigned ua, unsigned ub) {
    ua = (ua + 0x7FFFu + ((ua >> 16) & 1u)) >> 16;
    ub = (ub + 0x7FFFu + ((ub >> 16) & 1u)) >> 16;
    return ua | (ub << 16);
}
__device__ __forceinline__ unsigned pack_bf16(float a, float b) {
    return pack_bf16_bits(__float_as_uint(a), __float_as_uint(b));
}
__device__ __forceinline__ float2 unpack_bf16(unsigned u) {
    return make_float2(__uint_as_float(u << 16), __uint_as_float(u & 0xFFFF0000u));
}
__device__ __forceinline__ float rdlane_f(float x, int l) {
    return __uint_as_float((unsigned)__builtin_amdgcn_readlane((int)__float_as_uint(x), l));
}

// ---------- scalar-pipe metadata loads (wave-uniform) ----------
__device__ __forceinline__ void sload_pair(uvec16 &a, uvec16 &b, const void* p) {
    asm volatile("s_load_dwordx16 %0, %2, 0x0\n\t"
                 "s_load_dwordx16 %1, %2, 0x40\n\t"
                 "s_waitcnt lgkmcnt(0)"
                 : "=&s"(a), "=&s"(b) : "s"(p) : "memory");
}
__device__ __forceinline__ void sload_be(uvec2 &r, const void* p) {
    asm volatile("s_load_dwordx2 %0, %1, 0x0\n\t"
                 "s_waitcnt lgkmcnt(0)"
                 : "=&s"(r) : "s"(p) : "memory");
}

// process 8 edges from an SGPR chunk; lim = valid count (scalar).
// Invalid slots: index AND weight gated scalar-side -> load row 0 (L1-hot).
// Loads stay branchless -> batch issues in parallel (round-5 lesson).
__device__ __forceinline__ void chunk8(const uvec16 &m, int lim, int lane,
                                       const uint* __restrict__ srcBf,
                                       float &ax, float &ay, float &bx, float &by) {
    #pragma unroll
    for (int j = 0; j < 8; j++) {
        unsigned sx = (j < lim) ? (m[2 * j] & 0x3FFFFu) : 0u;
        float vv = (j < lim) ? __uint_as_float(m[2 * j + 1]) : 0.0f;
        const uint* p = srcBf + ((size_t)sx << 6);   // uniform base -> saddr load
        float2 uu = unpack_bf16(p[lane]);
        if (j & 1) { bx += vv * uu.x; by += vv * uu.y; }
        else       { ax += vv * uu.x; ay += vv * uu.y; }
    }
}

// ---------- fused: ego fp32 -> bf16 (blocks < CONV_BLOCKS) || coarse hist ----------
__global__ __launch_bounds__(256) void conv_hist(const float* __restrict__ in,
                                                 uint* __restrict__ outp,
                                                 const int* __restrict__ rows,
                                                 const int* __restrict__ cols,
                                                 int* __restrict__ cnt1,
                                                 int* __restrict__ cnt2) {
    __shared__ int h[512];
    int t = threadIdx.x;
    if (blockIdx.x < CONV_BLOCKS) {
        int i = blockIdx.x * 256 + t;                // exactly N*D/8 threads
        const u64* in8 = (const u64*)in;
        u64 w0 = __builtin_nontemporal_load(&in8[4 * i + 0]);
        u64 w1 = __builtin_nontemporal_load(&in8[4 * i + 1]);
        u64 w2 = __builtin_nontemporal_load(&in8[4 * i + 2]);
        u64 w3 = __builtin_nontemporal_load(&in8[4 * i + 3]);
        uint4 o;
        o.x = pack_bf16_bits((unsigned)w0, (unsigned)(w0 >> 32));
        o.y = pack_bf16_bits((unsigned)w1, (unsigned)(w1 >> 32));
        o.z = pack_bf16_bits((unsigned)w2, (unsigned)(w2 >> 32));
        o.w = pack_bf16_bits((unsigned)w3, (unsigned)(w3 >> 32));
        ((uint4*)outp)[i] = o;
    } else {
        h[t] = 0; h[t + 256] = 0;
        __syncthreads();
        int bid = blockIdx.x - CONV_BLOCKS;
        int stride = HIST_BLOCKS * 256;
        for (int e = bid * 256 + t; e < NNZ_E; e += stride) {
            atomicAdd(&h[cols[e] / DPB], 1);          // pass-1 dest = col
            atomicAdd(&h[256 + rows[e] / DPB], 1);    // pass-2 dest = row
        }
        __syncthreads();
        if (h[t]) atomicAdd(&cnt1[t], h[t]);
        if (h[t + 256]) atomicAdd(&cnt2[t], h[t + 256]);
    }
}

// ---------- fused phase A: dual inline scan + rank-based bin -> slab ----------
__global__ __launch_bounds__(512) void phaseA_fused(const int* __restrict__ rows,
                                                    const int* __restrict__ cols,
                                                    const float* __restrict__ vals,
                                                    const int* __restrict__ gcnt,
                                                    int* __restrict__ gCur,
                                                    int* __restrict__ sbG,
                                                    uint2* __restrict__ slab) {
    __shared__ uint2 sortedL[2 * EPB2];          // 32 KB
    __shared__ unsigned short bktL[2 * EPB2];    // 8 KB
    __shared__ int cnt[512], off[512], gbase[512];  // 6 KB
    __shared__ int part[512];                    // 2 KB
    __shared__ int sbL[513];                     // 2 KB
    __shared__ int totE;
    int t = threadIdx.x;
    int base = blockIdx.x * EPB2;
    cnt[t] = 0;

    // dual inline scan of hist counts: dir1 in threads 0-255, dir2 in 256-511
    int g = gcnt[t];
    part[t] = g; __syncthreads();
    for (int o = 1; o < 256; o <<= 1) {
        int a = ((t & 255) >= o) ? part[t - o] : 0; __syncthreads();
        part[t] += a; __syncthreads();
    }
    sbL[t] = ((t < 256) ? 0 : NNZ_E) + part[t] - g;
    if (t == 0) sbL[512] = 2 * NNZ_E;
    if (blockIdx.x == 0) {                       // publish for phaseB
        sbG[t] = sbL[t];
        if (t == 0) sbG[512] = 2 * NNZ_E;
    }
    __syncthreads();

    uint2 eA[4], eB[4];
    int rA[4], rB[4];
    short bA[4], bB[4];
    #pragma unroll
    for (int j = 0; j < 4; j++) {
        int e = base + j * 512 + t;
        if (e < NNZ_E) {
            int r = rows[e], c = cols[e];
            unsigned v = __float_as_uint(vals[e]);
            int b1 = c / DPB, dl1 = c - b1 * DPB;     // pass-1 dest = col, src = row
            int b2 = r / DPB, dl2 = r - b2 * DPB;     // pass-2 dest = row, src = col
            bA[j] = (short)b1;
            eA[j].x = ((unsigned)dl1 << 18) | (unsigned)r;
            eA[j].y = v;
            bB[j] = (short)(256 + b2);
            eB[j].x = ((unsigned)dl2 << 18) | (unsigned)c;
            eB[j].y = v;
            rA[j] = atomicAdd(&cnt[b1], 1);           // rank within (block,bucket)
            rB[j] = atomicAdd(&cnt[256 + b2], 1);
        } else { bA[j] = -1; bB[j] = -1; }
    }
    __syncthreads();
    // scan cnt(512), one per thread
    int c0 = cnt[t];
    part[t] = c0; __syncthreads();
    for (int o = 1; o < 512; o <<= 1) {
        int a = (t >= o) ? part[t - o] : 0; __syncthreads();
        part[t] += a; __syncthreads();
    }
    int bs = part[t] - c0;
    off[t] = bs;
    if (t == 511) totE = part[t];
    __syncthreads();
    // rank-based scatter into LDS: no second atomic pass
    #pragma unroll
    for (int j = 0; j < 4; j++) {
        if (bA[j] >= 0) {
            int p = off[(int)bA[j]] + rA[j];
            sortedL[p] = eA[j]; bktL[p] = (unsigned short)bA[j];
            p = off[(int)bB[j]] + rB[j];
            sortedL[p] = eB[j]; bktL[p] = (unsigned short)bB[j];
        }
    }
    __syncthreads();
    // reserve global slab space, one atomic per non-empty bucket
    if (cnt[t] > 0) gbase[t] = atomicAdd(&gCur[t], cnt[t]);
    __syncthreads();
    int nE = totE;
    for (int i = t; i < nE; i += 512) {
        int b = bktL[i];
        slab[sbL[b] + gbase[b] + (i - off[b])] = sortedL[i];
    }
}

// ---------- phase B: single slab read, rank-based emit, offs write ----------
__global__ __launch_bounds__(512) void phaseB(const uint2* __restrict__ slab,
                                              const int* __restrict__ slabBase,
                                              int* __restrict__ offs1,
                                              int* __restrict__ offs2,
                                              uint2* __restrict__ sorted) {
    __shared__ int cnt[DPB], sc[DPB], cur[DPB], part[512];
    int b = blockIdx.x, t = threadIdx.x;
    int sb = slabBase[b], se = slabBase[b + 1];
    int n = se - sb;
    for (int d = t; d < DPB; d += 512) cnt[d] = 0;
    __syncthreads();
    bool fast = (n <= 512 * MAXE);   // Poisson(5860): always true; guard anyway
    uint2 ent[MAXE]; int rk[MAXE];
    if (fast) {
        #pragma unroll
        for (int k = 0; k < MAXE; k++) {           // static idx -> registers (rule #20)
            int i = t + k * 512;
            bool valid = i < n;                    // OOB reads stay inside ws region
            uint2 e = valid ? slab[sb + i] : make_uint2(0u, 0u);
            ent[k] = e;
            rk[k] = valid ? atomicAdd(&cnt[e.x >> 18], 1) : 0;
        }
    } else {
        for (int i = t; i < n; i += 512)
            atomicAdd(&cnt[slab[sb + i].x >> 18], 1);
    }
    __syncthreads();
    int d0 = 2 * t;
    int c0 = (d0     < DPB) ? cnt[d0]     : 0;
    int c1 = (d0 + 1 < DPB) ? cnt[d0 + 1] : 0;
    int ps = c0 + c1;
    part[t] = ps; __syncthreads();
    for (int o = 1; o < 512; o <<= 1) {
        int a = (t >= o) ? part[t - o] : 0; __syncthreads();
        part[t] += a; __syncthreads();
    }
    int bs = part[t] - ps;
    if (d0     < DPB) { sc[d0]     = bs;      cur[d0]     = bs; }
    if (d0 + 1 < DPB) { sc[d0 + 1] = bs + c0; cur[d0 + 1] = bs + c0; }
    __syncthreads();
    int destBase = (b & 255) * DPB;
    int* offs = (b < NBUCK) ? offs1 : offs2;
    for (int d = t; d < DPB; d += 512) {
        int dd = destBase + d;
        if (dd <= N_TOTAL) offs[dd] = sb + sc[d];   // absolute index into sorted[]
    }
    if (fast) {
        #pragma unroll
        for (int k = 0; k < MAXE; k++) {
            int i = t + k * 512;
            if (i < n) {
                int dl = ent[k].x >> 18;
                sorted[sb + sc[dl] + rk[k]] = make_uint2(ent[k].x & 0x3FFFF, ent[k].y);
            }
        }
    } else {
        for (int i = t; i < n; i += 512) {
            uint2 e = slab[sb + i];
            int dl = e.x >> 18;
            int p = atomicAdd(&cur[dl], 1);
            sorted[sb + p] = make_uint2(e.x & 0x3FFFF, e.y);
        }
    }
}

// ---------- gather 1: SGPR metadata, saddr gathers, bf16 in/out ----------
__global__ __launch_bounds__(256) void gather1(const uint* __restrict__ srcBf,
                                               const int* __restrict__ offs,
                                               const uint2* __restrict__ edges,
                                               uint* __restrict__ dstBf) {
    int lane = threadIdx.x & 63;
    int row = blockIdx.x * 4 + (threadIdx.x >> 6);      // grid covers exactly N_TOTAL
    int row_u = __builtin_amdgcn_readfirstlane(row);
    uvec2 be;
    sload_be(be, offs + row_u);
    int beg = (int)be[0];
    int n = (int)be[1] - beg;
    const u64* ep = (const u64*)edges + beg;
    uvec16 mA, mB;
    sload_pair(mA, mB, ep);                             // <=128B past array end stays in ws
    float ax = 0.f, ay = 0.f, bx = 0.f, by = 0.f;
    chunk8(mA, n < 8 ? n : 8, lane, srcBf, ax, ay, bx, by);
    if (n > 8) {
        chunk8(mB, n - 8 < 8 ? n - 8 : 8, lane, srcBf, ax, ay, bx, by);
        if (n > 16) {
            uvec16 mC, mD;
            sload_pair(mC, mD, ep + 16);
            chunk8(mC, n - 16 < 8 ? n - 16 : 8, lane, srcBf, ax, ay, bx, by);
            if (n > 24) {
                chunk8(mD, n - 24 < 8 ? n - 24 : 8, lane, srcBf, ax, ay, bx, by);
                for (int k = 32; k < n; k++) {          // statistically never
                    uint2 e = edges[beg + k];
                    float v = __uint_as_float(e.y);
                    float2 u = unpack_bf16(srcBf[(((size_t)e.x) << 6) + lane]);
                    ax += v * u.x; ay += v * u.y;
                }
            }
        }
    }
    dstBf[(size_t)row_u * 64 + lane] = pack_bf16(ax + bx, ay + by);
}

// ---------- gather 2 + LN + residual: SGPR metadata, saddr gathers ----------
__global__ __launch_bounds__(256) void gather2_ln(const uint* __restrict__ hBf,
                                                  const int* __restrict__ offs,
                                                  const uint2* __restrict__ edges,
                                                  const uint* __restrict__ egoBf,
                                                  const float* __restrict__ gamma,
                                                  const float* __restrict__ beta,
                                                  float* __restrict__ out) {
    int lane = threadIdx.x & 63;
    int row = blockIdx.x * 4 + (threadIdx.x >> 6);
    int row_u = __builtin_amdgcn_readfirstlane(row);
    uvec2 be;
    sload_be(be, offs + row_u);
    int beg = (int)be[0];
    int n = (int)be[1] - beg;
    const u64* ep = (const u64*)edges + beg;
    uvec16 mA, mB;
    sload_pair(mA, mB, ep);
    float ax = 0.f, ay = 0.f, bx = 0.f, by = 0.f;
    chunk8(mA, n < 8 ? n : 8, lane, hBf, ax, ay, bx, by);
    if (n > 8) {
        chunk8(mB, n - 8 < 8 ? n - 8 : 8, lane, hBf, ax, ay, bx, by);
        if (n > 16) {
            uvec16 mC, mD;
            sload_pair(mC, mD, ep + 16);
            chunk8(mC, n - 16 < 8 ? n - 16 : 8, lane, hBf, ax, ay, bx, by);
            if (n > 24) {
                chunk8(mD, n - 24 < 8 ? n - 24 : 8, lane, hBf, ax, ay, bx, by);
                for (int k = 32; k < n; k++) {
                    uint2 e = edges[beg + k];
                    float v = __uint_as_float(e.y);
                    float2 u = unpack_bf16(hBf[(((size_t)e.x) << 6) + lane]);
                    ax += v * u.x; ay += v * u.y;
                }
            }
        }
    }
    float2 acc = make_float2(ax + bx, ay + by);
    float s = acc.x + acc.y;
    float sq = acc.x * acc.x + acc.y * acc.y;
    #pragma unroll
    for (int o = 1; o <= 16; o <<= 1) {
        s  += __shfl_xor(s, o, 64);
        sq += __shfl_xor(sq, o, 64);
    }
    // lanes 0 and 32 hold the two half-sums -> finish with scalar readlanes
    float sT  = rdlane_f(s, 0)  + rdlane_f(s, 32);
    float sqT = rdlane_f(sq, 0) + rdlane_f(sq, 32);
    float mu = sT * (1.0f / DIM);
    float var = sqT * (1.0f / DIM) - mu * mu;
    float rs = rsqrtf(var + 1e-5f);
    float2 g  = ((const float2*)gamma)[lane];
    float2 bb = ((const float2*)beta)[lane];
    unsigned egoW = __builtin_nontemporal_load(&egoBf[(size_t)row_u * 64 + lane]);
    float2 e2 = unpack_bf16(egoW);
    float2 o2;
    o2.x = (acc.x - mu) * rs * g.x + bb.x + e2.x;
    o2.y = (acc.y - mu) * rs * g.y + bb.y + e2.y;
    u64 ow = (u64)__float_as_uint(o2.x) | ((u64)__float_as_uint(o2.y) << 32);
    __builtin_nontemporal_store(ow, (u64*)out + (size_t)row_u * 64 + lane);
}

// ---------- fallback: atomic scatter path (ws too small) ----------
__device__ __forceinline__ void atomic_add_f32(float* p, float v) {
    __hip_atomic_fetch_add(p, v, __ATOMIC_RELAXED, __HIP_MEMORY_SCOPE_AGENT);
}
__global__ void scatter_kernel(const float* __restrict__ src, const float* __restrict__ vals,
                               const int* __restrict__ gidx, const int* __restrict__ sidx,
                               float* __restrict__ dst, int nnz) {
    int gid = blockIdx.x * blockDim.x + threadIdx.x;
    int e = gid >> 5, lane = gid & 31;
    if (e >= nnz) return;
    float v = vals[e];
    float4 x = ((const float4*)(src + (size_t)gidx[e] * DIM))[lane];
    float* d = dst + (size_t)sidx[e] * DIM + lane * 4;
    atomic_add_f32(d + 0, v * x.x); atomic_add_f32(d + 1, v * x.y);
    atomic_add_f32(d + 2, v * x.z); atomic_add_f32(d + 3, v * x.w);
}
__global__ void ln_residual_kernel(const float* __restrict__ h2, const float* __restrict__ ego,
                                   const float* __restrict__ gamma, const float* __restrict__ beta,
                                   float* __restrict__ out, int nrows) {
    int gid = blockIdx.x * blockDim.x + threadIdx.x;
    int row = gid >> 6, lane = gid & 63;
    if (row >= nrows) return;
    float2 x = ((const float2*)(h2 + (size_t)row * DIM))[lane];
    float s = x.x + x.y, sq = x.x * x.x + x.y * x.y;
    #pragma unroll
    for (int o = 32; o > 0; o >>= 1) { s += __shfl_xor(s, o, 64); sq += __shfl_xor(sq, o, 64); }
    float mu = s * (1.0f / DIM), var = sq * (1.0f / DIM) - mu * mu;
    float rs = rsqrtf(var + 1e-5f);
    float2 eg = ((const float2*)(ego + (size_t)row * DIM))[lane];
    float2 g = ((const float2*)gamma)[lane], b = ((const float2*)beta)[lane];
    float2 o2;
    o2.x = (x.x - mu) * rs * g.x + b.x + eg.x;
    o2.y = (x.y - mu) * rs * g.y + b.y + eg.y;
    ((float2*)(out + (size_t)row * DIM))[lane] = o2;
}

// ---------- launch ----------
extern "C" void kernel_launch(void* const* d_in, const int* in_sizes, int n_in,
                              void* d_out, int out_size, void* d_ws, size_t ws_size,
                              hipStream_t stream) {
    const float* ego   = (const float*)d_in[0];
    const float* vals  = (const float*)d_in[1];
    const float* gamma = (const float*)d_in[2];
    const float* beta  = (const float*)d_in[3];
    const int*   rows  = (const int*)d_in[4];
    const int*   cols  = (const int*)d_in[5];
    float* out = (float*)d_out;

    const size_t EGO_BF_B = (size_t)N_TOTAL * DIM * 2;               // 38.4 MB
    const size_t SLAB_B   = (size_t)2 * NNZ_E * sizeof(uint2);       // 24 MB
    const size_t H_BF_B   = (size_t)N_TOTAL * DIM * 2;               // 38.4 MB
    const size_t REGION_B = (SLAB_B > H_BF_B) ? SLAB_B : H_BF_B;     // hBf aliases dead slab
    const size_t SORT_B   = (size_t)2 * NNZ_E * sizeof(uint2);       // 24 MB
    const size_t OFFS_B   = ((size_t)N_TOTAL + 16) * sizeof(int);    // ~0.6 MB each
    const size_t SMALL    = 16384;
    const size_t REQ = EGO_BF_B + REGION_B + SORT_B + 2 * OFFS_B + SMALL;   // ~102 MB
    const size_t H_FP32_B = (size_t)N_TOTAL * DIM * sizeof(float);   // fallback: 76.8 MB

    char* w = (char*)d_ws;
    uint* egoBf   = (uint*)w;   w += EGO_BF_B;
    char* region  = w;          w += REGION_B;
    uint2* slab   = (uint2*)region;      // live: phaseA_fused -> phaseB
    uint* hBf     = (uint*)region;       // live: gather1 -> gather2 (slab dead by then)
    uint2* sorted = (uint2*)w;  w += SORT_B;
    int* offs1    = (int*)w;    w += OFFS_B;
    int* offs2    = (int*)w;    w += OFFS_B;
    int* cntArr   = (int*)w;    w += 512 * sizeof(int);   // cntArr + gc contiguous: one memset
    int* gc       = (int*)w;    w += 512 * sizeof(int);
    int* sb       = (int*)w;    w += 516 * sizeof(int);

    if (ws_size >= REQ) {
        (void)hipMemsetAsync(cntArr, 0, 1024 * sizeof(int), stream);
        conv_hist<<<CONV_BLOCKS + HIST_BLOCKS, 256, 0, stream>>>(ego, egoBf, rows, cols,
                                                                 cntArr, cntArr + 256);
        phaseA_fused<<<A2_BLOCKS, 512, 0, stream>>>(rows, cols, vals, cntArr, gc, sb, slab);
        phaseB<<<512, 512, 0, stream>>>(slab, sb, offs1, offs2, sorted);

        int ggrid = (N_TOTAL + 3) / 4;      // 4 waves/block, 1 row/wave -> 37500
        gather1<<<ggrid, 256, 0, stream>>>(egoBf, offs1, sorted, hBf);
        gather2_ln<<<ggrid, 256, 0, stream>>>(hBf, offs2, sorted, egoBf, gamma, beta, out);
    } else {
        float* h = (float*)d_ws;            // fallback: fp32 h at ws start
        (void)hipMemsetAsync(h, 0, H_FP32_B, stream);
        (void)hipMemsetAsync(out, 0, H_FP32_B, stream);
        long total = (long)NNZ_E * 32;
        int grid = (int)((total + 255) / 256);
        scatter_kernel<<<grid, 256, 0, stream>>>(ego, vals, rows, cols, h, NNZ_E);
        scatter_kernel<<<grid, 256, 0, stream>>>(h, vals, cols, rows, out, NNZ_E);
        int lngrid = (N_TOTAL * 64 + 255) / 256;
        ln_residual_kernel<<<lngrid, 256, 0, stream>>>(out, ego, gamma, beta, out, N_TOTAL);
    }
}

// Round 11
// 335.702 us; speedup vs baseline: 15.3841x; 1.0091x over previous
//
#include <hip/hip_runtime.h>

#define N_TOTAL 150000
#define DIM 128
#define NNZ_E 1500000
#define NBUCK 256
#define DPB 586                 // dests per bucket: 256*586 = 150016 >= 150000
#define EPB2 2048               // edges per fused phase-A block (emits 2 entries each)
#define A2_BLOCKS ((NNZ_E + EPB2 - 1) / EPB2)   // 733
#define CONV_BLOCKS 9375        // N_TOTAL*DIM/8 / 256
#define HIST_BLOCKS 512
#define MAXE 16                 // phaseB1 register slots/thread: 512*16=8192 >= max bucket n
#define G1_BLOCKS (N_TOTAL / 8) // 18750: gather1 rows per fused launch

typedef unsigned long long u64;
typedef unsigned uvec16 __attribute__((ext_vector_type(16)));
typedef unsigned uvec2  __attribute__((ext_vector_type(2)));

// ---------- bf16 pack/unpack (RNE) ----------
__device__ __forceinline__ unsigned pack_bf16_bits(unsigned ua, unsigned ub) {
    ua = (ua + 0x7FFFu + ((ua >> 16) & 1u)) >> 16;
    ub = (ub + 0x7FFFu + ((ub >> 16) & 1u)) >> 16;
    return ua | (ub << 16);
}
__device__ __forceinline__ unsigned pack_bf16(float a, float b) {
    return pack_bf16_bits(__float_as_uint(a), __float_as_uint(b));
}
__device__ __forceinline__ float2 unpack_bf16(unsigned u) {
    return make_float2(__uint_as_float(u << 16), __uint_as_float(u & 0xFFFF0000u));
}
__device__ __forceinline__ float rdlane_f(float x, int l) {
    return __uint_as_float((unsigned)__builtin_amdgcn_readlane((int)__float_as_uint(x), l));
}

// ---------- scalar-pipe metadata loads (wave-uniform) ----------
__device__ __forceinline__ void sload_pair(uvec16 &a, uvec16 &b, const void* p) {
    asm volatile("s_load_dwordx16 %0, %2, 0x0\n\t"
                 "s_load_dwordx16 %1, %2, 0x40\n\t"
                 "s_waitcnt lgkmcnt(0)"
                 : "=&s"(a), "=&s"(b) : "s"(p) : "memory");
}
__device__ __forceinline__ void sload_be(uvec2 &r, const void* p) {
    asm volatile("s_load_dwordx2 %0, %1, 0x0\n\t"
                 "s_waitcnt lgkmcnt(0)"
                 : "=&s"(r) : "s"(p) : "memory");
}

// process 8 edges from an SGPR chunk; lim = valid count (scalar).
// Invalid slots: index AND weight gated scalar-side -> load row 0 (L1-hot).
// Loads stay branchless -> batch issues in parallel (round-5 lesson).
__device__ __forceinline__ void chunk8(const uvec16 &m, int lim, int lane,
                                       const uint* __restrict__ srcBf,
                                       float &ax, float &ay, float &bx, float &by) {
    #pragma unroll
    for (int j = 0; j < 8; j++) {
        unsigned sx = (j < lim) ? (m[2 * j] & 0x3FFFFu) : 0u;
        float vv = (j < lim) ? __uint_as_float(m[2 * j + 1]) : 0.0f;
        const uint* p = srcBf + ((size_t)sx << 6);   // uniform base -> saddr load
        float2 uu = unpack_bf16(p[lane]);
        if (j & 1) { bx += vv * uu.x; by += vv * uu.y; }
        else       { ax += vv * uu.x; ay += vv * uu.y; }
    }
}

// shared gather-row body (reads edge metadata into SGPRs, accumulates one row)
__device__ __forceinline__ void gather_row(const uint* __restrict__ srcBf,
                                           const int* __restrict__ offs,
                                           const uint2* __restrict__ edges,
                                           int row_u, int lane,
                                           float &ax, float &ay, float &bx, float &by) {
    uvec2 be;
    sload_be(be, offs + row_u);
    int beg = (int)be[0];
    int n = (int)be[1] - beg;
    const u64* ep = (const u64*)edges + beg;
    uvec16 mA, mB;
    sload_pair(mA, mB, ep);                       // <=128B past region stays in ws
    chunk8(mA, n < 8 ? n : 8, lane, srcBf, ax, ay, bx, by);
    if (n > 8) {
        chunk8(mB, n - 8 < 8 ? n - 8 : 8, lane, srcBf, ax, ay, bx, by);
        if (n > 16) {
            uvec16 mC, mD;
            sload_pair(mC, mD, ep + 16);
            chunk8(mC, n - 16 < 8 ? n - 16 : 8, lane, srcBf, ax, ay, bx, by);
            if (n > 24) {
                chunk8(mD, n - 24 < 8 ? n - 24 : 8, lane, srcBf, ax, ay, bx, by);
                for (int k = 32; k < n; k++) {    // statistically never
                    uint2 e = edges[beg + k];
                    float v = __uint_as_float(e.y);
                    float2 u = unpack_bf16(srcBf[(((size_t)e.x) << 6) + lane]);
                    ax += v * u.x; ay += v * u.y;
                }
            }
        }
    }
}

// ---------- fused: ego fp32 -> bf16 (blocks < CONV_BLOCKS) || coarse hist ----------
__global__ __launch_bounds__(256) void conv_hist(const float* __restrict__ in,
                                                 uint* __restrict__ outp,
                                                 const int* __restrict__ rows,
                                                 const int* __restrict__ cols,
                                                 int* __restrict__ cnt1,
                                                 int* __restrict__ cnt2) {
    __shared__ int h[512];
    int t = threadIdx.x;
    if (blockIdx.x < CONV_BLOCKS) {
        int i = blockIdx.x * 256 + t;                // exactly N*D/8 threads
        const u64* in8 = (const u64*)in;
        u64 w0 = __builtin_nontemporal_load(&in8[4 * i + 0]);
        u64 w1 = __builtin_nontemporal_load(&in8[4 * i + 1]);
        u64 w2 = __builtin_nontemporal_load(&in8[4 * i + 2]);
        u64 w3 = __builtin_nontemporal_load(&in8[4 * i + 3]);
        uint4 o;
        o.x = pack_bf16_bits((unsigned)w0, (unsigned)(w0 >> 32));
        o.y = pack_bf16_bits((unsigned)w1, (unsigned)(w1 >> 32));
        o.z = pack_bf16_bits((unsigned)w2, (unsigned)(w2 >> 32));
        o.w = pack_bf16_bits((unsigned)w3, (unsigned)(w3 >> 32));
        ((uint4*)outp)[i] = o;
    } else {
        h[t] = 0; h[t + 256] = 0;
        __syncthreads();
        int bid = blockIdx.x - CONV_BLOCKS;
        int stride = HIST_BLOCKS * 256;
        for (int e = bid * 256 + t; e < NNZ_E; e += stride) {
            atomicAdd(&h[cols[e] / DPB], 1);          // pass-1 dest = col
            atomicAdd(&h[256 + rows[e] / DPB], 1);    // pass-2 dest = row
        }
        __syncthreads();
        if (h[t]) atomicAdd(&cnt1[t], h[t]);
        if (h[t + 256]) atomicAdd(&cnt2[t], h[t + 256]);
    }
}

// ---------- fused phase A: dual inline scan + rank-based bin -> slab ----------
__global__ __launch_bounds__(512) void phaseA_fused(const int* __restrict__ rows,
                                                    const int* __restrict__ cols,
                                                    const float* __restrict__ vals,
                                                    const int* __restrict__ gcnt,
                                                    int* __restrict__ gCur,
                                                    int* __restrict__ sbG,
                                                    uint2* __restrict__ slab) {
    __shared__ uint2 sortedL[2 * EPB2];          // 32 KB
    __shared__ unsigned short bktL[2 * EPB2];    // 8 KB
    __shared__ int cnt[512], off[512], gbase[512];  // 6 KB
    __shared__ int part[512];                    // 2 KB
    __shared__ int sbL[513];                     // 2 KB
    __shared__ int totE;
    int t = threadIdx.x;
    int base = blockIdx.x * EPB2;
    cnt[t] = 0;

    // dual inline scan of hist counts: dir1 in threads 0-255, dir2 in 256-511
    int g = gcnt[t];
    part[t] = g; __syncthreads();
    for (int o = 1; o < 256; o <<= 1) {
        int a = ((t & 255) >= o) ? part[t - o] : 0; __syncthreads();
        part[t] += a; __syncthreads();
    }
    sbL[t] = ((t < 256) ? 0 : NNZ_E) + part[t] - g;
    if (t == 0) sbL[512] = 2 * NNZ_E;
    if (blockIdx.x == 0) {                       // publish for phaseB
        sbG[t] = sbL[t];
        if (t == 0) sbG[512] = 2 * NNZ_E;
    }
    __syncthreads();

    uint2 eA[4], eB[4];
    int rA[4], rB[4];
    short bA[4], bB[4];
    #pragma unroll
    for (int j = 0; j < 4; j++) {
        int e = base + j * 512 + t;
        if (e < NNZ_E) {
            int r = rows[e], c = cols[e];
            unsigned v = __float_as_uint(vals[e]);
            int b1 = c / DPB, dl1 = c - b1 * DPB;     // pass-1 dest = col, src = row
            int b2 = r / DPB, dl2 = r - b2 * DPB;     // pass-2 dest = row, src = col
            bA[j] = (short)b1;
            eA[j].x = ((unsigned)dl1 << 18) | (unsigned)r;
            eA[j].y = v;
            bB[j] = (short)(256 + b2);
            eB[j].x = ((unsigned)dl2 << 18) | (unsigned)c;
            eB[j].y = v;
            rA[j] = atomicAdd(&cnt[b1], 1);           // rank within (block,bucket)
            rB[j] = atomicAdd(&cnt[256 + b2], 1);
        } else { bA[j] = -1; bB[j] = -1; }
    }
    __syncthreads();
    // scan cnt(512), one per thread
    int c0 = cnt[t];
    part[t] = c0; __syncthreads();
    for (int o = 1; o < 512; o <<= 1) {
        int a = (t >= o) ? part[t - o] : 0; __syncthreads();
        part[t] += a; __syncthreads();
    }
    int bs = part[t] - c0;
    off[t] = bs;
    if (t == 511) totE = part[t];
    __syncthreads();
    // rank-based scatter into LDS: no second atomic pass
    #pragma unroll
    for (int j = 0; j < 4; j++) {
        if (bA[j] >= 0) {
            int p = off[(int)bA[j]] + rA[j];
            sortedL[p] = eA[j]; bktL[p] = (unsigned short)bA[j];
            p = off[(int)bB[j]] + rB[j];
            sortedL[p] = eB[j]; bktL[p] = (unsigned short)bB[j];
        }
    }
    __syncthreads();
    // reserve global slab space, one atomic per non-empty bucket
    if (cnt[t] > 0) gbase[t] = atomicAdd(&gCur[t], cnt[t]);
    __syncthreads();
    int nE = totE;
    for (int i = t; i < nE; i += 512) {
        int b = bktL[i];
        slab[sbL[b] + gbase[b] + (i - off[b])] = sortedL[i];
    }
}

// ---------- phase B dir-1 only: single slab read, rank-based emit ----------
__global__ __launch_bounds__(512) void phaseB1(const uint2* __restrict__ slab,
                                               const int* __restrict__ slabBase,
                                               int* __restrict__ offs1,
                                               uint2* __restrict__ sorted) {
    __shared__ int cnt[DPB], sc[DPB], cur[DPB], part[512];
    int b = blockIdx.x, t = threadIdx.x;     // b in [0, 256): dir-1 buckets
    int sb = slabBase[b], se = slabBase[b + 1];
    int n = se - sb;
    for (int d = t; d < DPB; d += 512) cnt[d] = 0;
    __syncthreads();
    bool fast = (n <= 512 * MAXE);   // Poisson(5860): always true; guard anyway
    uint2 ent[MAXE]; int rk[MAXE];
    if (fast) {
        #pragma unroll
        for (int k = 0; k < MAXE; k++) {           // static idx -> registers (rule #20)
            int i = t + k * 512;
            bool valid = i < n;
            uint2 e = valid ? slab[sb + i] : make_uint2(0u, 0u);
            ent[k] = e;
            rk[k] = valid ? atomicAdd(&cnt[e.x >> 18], 1) : 0;
        }
    } else {
        for (int i = t; i < n; i += 512)
            atomicAdd(&cnt[slab[sb + i].x >> 18], 1);
    }
    __syncthreads();
    int d0 = 2 * t;
    int c0 = (d0     < DPB) ? cnt[d0]     : 0;
    int c1 = (d0 + 1 < DPB) ? cnt[d0 + 1] : 0;
    int ps = c0 + c1;
    part[t] = ps; __syncthreads();
    for (int o = 1; o < 512; o <<= 1) {
        int a = (t >= o) ? part[t - o] : 0; __syncthreads();
        part[t] += a; __syncthreads();
    }
    int bs = part[t] - ps;
    if (d0     < DPB) { sc[d0]     = bs;      cur[d0]     = bs; }
    if (d0 + 1 < DPB) { sc[d0 + 1] = bs + c0; cur[d0 + 1] = bs + c0; }
    __syncthreads();
    int destBase = b * DPB;
    for (int d = t; d < DPB; d += 512) {
        int dd = destBase + d;
        if (dd <= N_TOTAL) offs1[dd] = sb + sc[d];
    }
    if (fast) {
        #pragma unroll
        for (int k = 0; k < MAXE; k++) {
            int i = t + k * 512;
            if (i < n) {
                int dl = ent[k].x >> 18;
                sorted[sb + sc[dl] + rk[k]] = make_uint2(ent[k].x & 0x3FFFF, ent[k].y);
            }
        }
    } else {
        for (int i = t; i < n; i += 512) {
            uint2 e = slab[sb + i];
            int dl = e.x >> 18;
            int p = atomicAdd(&cur[dl], 1);
            sorted[sb + p] = make_uint2(e.x & 0x3FFFF, e.y);
        }
    }
}

// ---------- fused: phaseB dir-2 (blocks 0..255, 2-pass low-VGPR) || gather1 ----------
__global__ __launch_bounds__(512) void phaseB2_gather1(const uint2* __restrict__ slab,
                                                       const int* __restrict__ slabBase,
                                                       int* __restrict__ offs2,
                                                       uint2* __restrict__ sorted,
                                                       const uint* __restrict__ egoBf,
                                                       const int* __restrict__ offs1,
                                                       uint* __restrict__ hBf) {
    __shared__ int cnt[DPB], sc[DPB], cur[DPB], part[512];
    int t = threadIdx.x;
    if (blockIdx.x < NBUCK) {
        // ---- phaseB dir-2: hidden under gather1 occupancy ----
        int b = blockIdx.x + NBUCK;
        int sb = slabBase[b], se = slabBase[b + 1];
        int n = se - sb;
        for (int d = t; d < DPB; d += 512) cnt[d] = 0;
        __syncthreads();
        for (int i = t; i < n; i += 512)
            atomicAdd(&cnt[slab[sb + i].x >> 18], 1);
        __syncthreads();
        int d0 = 2 * t;
        int c0 = (d0     < DPB) ? cnt[d0]     : 0;
        int c1 = (d0 + 1 < DPB) ? cnt[d0 + 1] : 0;
        int ps = c0 + c1;
        part[t] = ps; __syncthreads();
        for (int o = 1; o < 512; o <<= 1) {
            int a = (t >= o) ? part[t - o] : 0; __syncthreads();
            part[t] += a; __syncthreads();
        }
        int bs = part[t] - ps;
        if (d0     < DPB) { sc[d0]     = bs;      cur[d0]     = bs; }
        if (d0 + 1 < DPB) { sc[d0 + 1] = bs + c0; cur[d0 + 1] = bs + c0; }
        __syncthreads();
        int destBase = blockIdx.x * DPB;
        for (int d = t; d < DPB; d += 512) {
            int dd = destBase + d;
            if (dd <= N_TOTAL) offs2[dd] = sb + sc[d];
        }
        for (int i = t; i < n; i += 512) {
            uint2 e = slab[sb + i];
            int dl = e.x >> 18;
            int p = atomicAdd(&cur[dl], 1);
            sorted[sb + p] = make_uint2(e.x & 0x3FFFF, e.y);
        }
    } else {
        // ---- gather1: 8 rows/block, 512 threads ----
        int lane = t & 63;
        int row = (blockIdx.x - NBUCK) * 8 + (t >> 6);   // exact: 18750*8 = N_TOTAL
        int row_u = __builtin_amdgcn_readfirstlane(row);
        float ax = 0.f, ay = 0.f, bx = 0.f, by = 0.f;
        gather_row(egoBf, offs1, sorted, row_u, lane, ax, ay, bx, by);
        hBf[(size_t)row_u * 64 + lane] = pack_bf16(ax + bx, ay + by);
    }
}

// ---------- gather 2 + LN + residual: SGPR metadata, saddr gathers ----------
__global__ __launch_bounds__(256) void gather2_ln(const uint* __restrict__ hBf,
                                                  const int* __restrict__ offs,
                                                  const uint2* __restrict__ edges,
                                                  const uint* __restrict__ egoBf,
                                                  const float* __restrict__ gamma,
                                                  const float* __restrict__ beta,
                                                  float* __restrict__ out) {
    int lane = threadIdx.x & 63;
    int row = blockIdx.x * 4 + (threadIdx.x >> 6);
    int row_u = __builtin_amdgcn_readfirstlane(row);
    float ax = 0.f, ay = 0.f, bx = 0.f, by = 0.f;
    gather_row(hBf, offs, edges, row_u, lane, ax, ay, bx, by);
    float2 acc = make_float2(ax + bx, ay + by);
    float s = acc.x + acc.y;
    float sq = acc.x * acc.x + acc.y * acc.y;
    #pragma unroll
    for (int o = 1; o <= 16; o <<= 1) {
        s  += __shfl_xor(s, o, 64);
        sq += __shfl_xor(sq, o, 64);
    }
    // lanes 0 and 32 hold the two half-sums -> finish with scalar readlanes
    float sT  = rdlane_f(s, 0)  + rdlane_f(s, 32);
    float sqT = rdlane_f(sq, 0) + rdlane_f(sq, 32);
    float mu = sT * (1.0f / DIM);
    float var = sqT * (1.0f / DIM) - mu * mu;
    float rs = rsqrtf(var + 1e-5f);
    float2 g  = ((const float2*)gamma)[lane];
    float2 bb = ((const float2*)beta)[lane];
    unsigned egoW = __builtin_nontemporal_load(&egoBf[(size_t)row_u * 64 + lane]);
    float2 e2 = unpack_bf16(egoW);
    float2 o2;
    o2.x = (acc.x - mu) * rs * g.x + bb.x + e2.x;
    o2.y = (acc.y - mu) * rs * g.y + bb.y + e2.y;
    u64 ow = (u64)__float_as_uint(o2.x) | ((u64)__float_as_uint(o2.y) << 32);
    __builtin_nontemporal_store(ow, (u64*)out + (size_t)row_u * 64 + lane);
}

// ---------- fallback: atomic scatter path (ws too small) ----------
__device__ __forceinline__ void atomic_add_f32(float* p, float v) {
    __hip_atomic_fetch_add(p, v, __ATOMIC_RELAXED, __HIP_MEMORY_SCOPE_AGENT);
}
__global__ void scatter_kernel(const float* __restrict__ src, const float* __restrict__ vals,
                               const int* __restrict__ gidx, const int* __restrict__ sidx,
                               float* __restrict__ dst, int nnz) {
    int gid = blockIdx.x * blockDim.x + threadIdx.x;
    int e = gid >> 5, lane = gid & 31;
    if (e >= nnz) return;
    float v = vals[e];
    float4 x = ((const float4*)(src + (size_t)gidx[e] * DIM))[lane];
    float* d = dst + (size_t)sidx[e] * DIM + lane * 4;
    atomic_add_f32(d + 0, v * x.x); atomic_add_f32(d + 1, v * x.y);
    atomic_add_f32(d + 2, v * x.z); atomic_add_f32(d + 3, v * x.w);
}
__global__ void ln_residual_kernel(const float* __restrict__ h2, const float* __restrict__ ego,
                                   const float* __restrict__ gamma, const float* __restrict__ beta,
                                   float* __restrict__ out, int nrows) {
    int gid = blockIdx.x * blockDim.x + threadIdx.x;
    int row = gid >> 6, lane = gid & 63;
    if (row >= nrows) return;
    float2 x = ((const float2*)(h2 + (size_t)row * DIM))[lane];
    float s = x.x + x.y, sq = x.x * x.x + x.y * x.y;
    #pragma unroll
    for (int o = 32; o > 0; o >>= 1) { s += __shfl_xor(s, o, 64); sq += __shfl_xor(sq, o, 64); }
    float mu = s * (1.0f / DIM), var = sq * (1.0f / DIM) - mu * mu;
    float rs = rsqrtf(var + 1e-5f);
    float2 eg = ((const float2*)(ego + (size_t)row * DIM))[lane];
    float2 g = ((const float2*)gamma)[lane], b = ((const float2*)beta)[lane];
    float2 o2;
    o2.x = (x.x - mu) * rs * g.x + b.x + eg.x;
    o2.y = (x.y - mu) * rs * g.y + b.y + eg.y;
    ((float2*)(out + (size_t)row * DIM))[lane] = o2;
}

// ---------- launch ----------
extern "C" void kernel_launch(void* const* d_in, const int* in_sizes, int n_in,
                              void* d_out, int out_size, void* d_ws, size_t ws_size,
                              hipStream_t stream) {
    const float* ego   = (const float*)d_in[0];
    const float* vals  = (const float*)d_in[1];
    const float* gamma = (const float*)d_in[2];
    const float* beta  = (const float*)d_in[3];
    const int*   rows  = (const int*)d_in[4];
    const int*   cols  = (const int*)d_in[5];
    float* out = (float*)d_out;

    const size_t EGO_BF_B = (size_t)N_TOTAL * DIM * 2;               // 38.4 MB
    const size_t H_BF_B   = (size_t)N_TOTAL * DIM * 2;               // 38.4 MB
    const size_t SORT_B   = (size_t)2 * NNZ_E * sizeof(uint2);       // 24 MB
    const size_t OFFS_B   = ((size_t)N_TOTAL + 16) * sizeof(int);    // ~0.6 MB each
    const size_t SMALL    = 16384;
    const size_t REQ = EGO_BF_B + H_BF_B + SORT_B + 2 * OFFS_B + SMALL;   // ~102 MB
    const size_t H_FP32_B = (size_t)N_TOTAL * DIM * sizeof(float);   // fallback: 76.8 MB

    char* w = (char*)d_ws;
    uint* egoBf   = (uint*)w;   w += EGO_BF_B;
    uint* hBf     = (uint*)w;   w += H_BF_B;              // own buffer (no slab alias now)
    uint2* sorted = (uint2*)w;  w += SORT_B;
    int* offs1    = (int*)w;    w += OFFS_B;
    int* offs2    = (int*)w;    w += OFFS_B;
    int* cntArr   = (int*)w;    w += 512 * sizeof(int);   // cntArr + gc contiguous: one memset
    int* gc       = (int*)w;    w += 512 * sizeof(int);
    int* sb       = (int*)w;    w += 516 * sizeof(int);
    uint2* slab   = (uint2*)d_out;    // 24 MB scratch in 76.8 MB output (r8-verified);
                                      // dead before gather2_ln writes out

    if (ws_size >= REQ) {
        (void)hipMemsetAsync(cntArr, 0, 1024 * sizeof(int), stream);
        conv_hist<<<CONV_BLOCKS + HIST_BLOCKS, 256, 0, stream>>>(ego, egoBf, rows, cols,
                                                                 cntArr, cntArr + 256);
        phaseA_fused<<<A2_BLOCKS, 512, 0, stream>>>(rows, cols, vals, cntArr, gc, sb, slab);
        phaseB1<<<NBUCK, 512, 0, stream>>>(slab, sb, offs1, sorted);
        // phaseB dir-2 rides along with gather1 (first 256 blocks, off critical path)
        phaseB2_gather1<<<NBUCK + G1_BLOCKS, 512, 0, stream>>>(slab, sb, offs2, sorted,
                                                               egoBf, offs1, hBf);
        gather2_ln<<<N_TOTAL / 4, 256, 0, stream>>>(hBf, offs2, sorted, egoBf,
                                                    gamma, beta, out);
    } else {
        float* h = (float*)d_ws;            // fallback: fp32 h at ws start
        (void)hipMemsetAsync(h, 0, H_FP32_B, stream);
        (void)hipMemsetAsync(out, 0, H_FP32_B, stream);
        long total = (long)NNZ_E * 32;
        int grid = (int)((total + 255) / 256);
        scatter_kernel<<<grid, 256, 0, stream>>>(ego, vals, rows, cols, h, NNZ_E);
        scatter_kernel<<<grid, 256, 0, stream>>>(h, vals, cols, rows, out, NNZ_E);
        int lngrid = (N_TOTAL * 64 + 255) / 256;
        ln_residual_kernel<<<lngrid, 256, 0, stream>>>(out, ego, gamma, beta, out, N_TOTAL);
    }
}

// Round 12
// 333.935 us; speedup vs baseline: 15.4655x; 1.0053x over previous
//
#include <hip/hip_runtime.h>

#define N_TOTAL 150000
#define DIM 128
#define NNZ_E 1500000
#define NBUCK 256
#define DPB 586                 // dests per bucket: 256*586 = 150016 >= 150000
#define EPB2 2048               // edges per fused phase-A block (emits 2 entries each)
#define A2_BLOCKS ((NNZ_E + EPB2 - 1) / EPB2)   // 733
#define CONV_BLOCKS 9375        // N_TOTAL*DIM/8 / 256
#define HIST_BLOCKS 512
#define MAXE 16                 // phaseB1 register slots/thread: 512*16=8192 >= max bucket n
#define G1_BLOCKS (N_TOTAL / 8) // 18750: gather1 rows per fused launch
#define SLAB_CAP 8192           // fixed slab slots/bucket (Poisson(5860): 30-sigma margin)

typedef unsigned long long u64;
typedef unsigned uvec16 __attribute__((ext_vector_type(16)));
typedef unsigned uvec2  __attribute__((ext_vector_type(2)));

// ---------- bf16 pack/unpack (RNE) ----------
__device__ __forceinline__ unsigned pack_bf16_bits(unsigned ua, unsigned ub) {
    ua = (ua + 0x7FFFu + ((ua >> 16) & 1u)) >> 16;
    ub = (ub + 0x7FFFu + ((ub >> 16) & 1u)) >> 16;
    return ua | (ub << 16);
}
__device__ __forceinline__ unsigned pack_bf16(float a, float b) {
    return pack_bf16_bits(__float_as_uint(a), __float_as_uint(b));
}
__device__ __forceinline__ float2 unpack_bf16(unsigned u) {
    return make_float2(__uint_as_float(u << 16), __uint_as_float(u & 0xFFFF0000u));
}
__device__ __forceinline__ float rdlane_f(float x, int l) {
    return __uint_as_float((unsigned)__builtin_amdgcn_readlane((int)__float_as_uint(x), l));
}

// ---------- hierarchical scan: wave shfl-scan + 8-wave fixup (2 barriers) ----------
__device__ __forceinline__ int wave_iscan(int v, int lane) {
    #pragma unroll
    for (int o = 1; o < 64; o <<= 1) {
        int u = __shfl_up(v, o, 64);
        if (lane >= o) v += u;
    }
    return v;
}
// exclusive scan of one value/thread across 512 threads; wsum[8] in LDS
__device__ __forceinline__ int blk_escan512(int v, int t, int* wsum) {
    int lane = t & 63, wv = t >> 6;
    int inc = wave_iscan(v, lane);
    if (lane == 63) wsum[wv] = inc;
    __syncthreads();
    if (t < 64) {
        int x = (t < 8) ? wsum[t] : 0;
        int p = wave_iscan(x, t);
        if (t < 8) wsum[t] = p - x;          // exclusive wave prefix
    }
    __syncthreads();
    return wsum[wv] + inc - v;
}

// ---------- scalar-pipe metadata loads (wave-uniform) ----------
__device__ __forceinline__ void sload_pair(uvec16 &a, uvec16 &b, const void* p) {
    asm volatile("s_load_dwordx16 %0, %2, 0x0\n\t"
                 "s_load_dwordx16 %1, %2, 0x40\n\t"
                 "s_waitcnt lgkmcnt(0)"
                 : "=&s"(a), "=&s"(b) : "s"(p) : "memory");
}
__device__ __forceinline__ void sload_be(uvec2 &r, const void* p) {
    asm volatile("s_load_dwordx2 %0, %1, 0x0\n\t"
                 "s_waitcnt lgkmcnt(0)"
                 : "=&s"(r) : "s"(p) : "memory");
}

// process 8 edges from an SGPR chunk; lim = valid count (scalar).
// Invalid slots: index AND weight gated scalar-side -> load row 0 (L1-hot).
// Loads stay branchless -> batch issues in parallel (round-5 lesson).
__device__ __forceinline__ void chunk8(const uvec16 &m, int lim, int lane,
                                       const uint* __restrict__ srcBf,
                                       float &ax, float &ay, float &bx, float &by) {
    #pragma unroll
    for (int j = 0; j < 8; j++) {
        unsigned sx = (j < lim) ? (m[2 * j] & 0x3FFFFu) : 0u;
        float vv = (j < lim) ? __uint_as_float(m[2 * j + 1]) : 0.0f;
        const uint* p = srcBf + ((size_t)sx << 6);   // uniform base -> saddr load
        float2 uu = unpack_bf16(p[lane]);
        if (j & 1) { bx += vv * uu.x; by += vv * uu.y; }
        else       { ax += vv * uu.x; ay += vv * uu.y; }
    }
}

// shared gather-row body (reads edge metadata into SGPRs, accumulates one row)
__device__ __forceinline__ void gather_row(const uint* __restrict__ srcBf,
                                           const int* __restrict__ offs,
                                           const uint2* __restrict__ edges,
                                           int row_u, int lane,
                                           float &ax, float &ay, float &bx, float &by) {
    uvec2 be;
    sload_be(be, offs + row_u);
    int beg = (int)be[0];
    int n = (int)be[1] - beg;
    const u64* ep = (const u64*)edges + beg;
    uvec16 mA, mB;
    sload_pair(mA, mB, ep);                       // <=256B past region stays in ws
    chunk8(mA, n < 8 ? n : 8, lane, srcBf, ax, ay, bx, by);
    if (n > 8) {
        chunk8(mB, n - 8 < 8 ? n - 8 : 8, lane, srcBf, ax, ay, bx, by);
        if (n > 16) {
            uvec16 mC, mD;
            sload_pair(mC, mD, ep + 16);
            chunk8(mC, n - 16 < 8 ? n - 16 : 8, lane, srcBf, ax, ay, bx, by);
            if (n > 24) {
                chunk8(mD, n - 24 < 8 ? n - 24 : 8, lane, srcBf, ax, ay, bx, by);
                for (int k = 32; k < n; k++) {    // statistically never
                    uint2 e = edges[beg + k];
                    float v = __uint_as_float(e.y);
                    float2 u = unpack_bf16(srcBf[(((size_t)e.x) << 6) + lane]);
                    ax += v * u.x; ay += v * u.y;
                }
            }
        }
    }
}

// ---------- fused: ego fp32 -> bf16 (blocks < CONV_BLOCKS) || coarse hist ----------
__global__ __launch_bounds__(256) void conv_hist(const float* __restrict__ in,
                                                 uint* __restrict__ outp,
                                                 const int* __restrict__ rows,
                                                 const int* __restrict__ cols,
                                                 int* __restrict__ cnt1,
                                                 int* __restrict__ cnt2) {
    __shared__ int h[512];
    int t = threadIdx.x;
    if (blockIdx.x < CONV_BLOCKS) {
        int i = blockIdx.x * 256 + t;                // exactly N*D/8 threads
        const u64* in8 = (const u64*)in;
        u64 w0 = __builtin_nontemporal_load(&in8[4 * i + 0]);
        u64 w1 = __builtin_nontemporal_load(&in8[4 * i + 1]);
        u64 w2 = __builtin_nontemporal_load(&in8[4 * i + 2]);
        u64 w3 = __builtin_nontemporal_load(&in8[4 * i + 3]);
        uint4 o;
        o.x = pack_bf16_bits((unsigned)w0, (unsigned)(w0 >> 32));
        o.y = pack_bf16_bits((unsigned)w1, (unsigned)(w1 >> 32));
        o.z = pack_bf16_bits((unsigned)w2, (unsigned)(w2 >> 32));
        o.w = pack_bf16_bits((unsigned)w3, (unsigned)(w3 >> 32));
        ((uint4*)outp)[i] = o;
    } else {
        h[t] = 0; h[t + 256] = 0;
        __syncthreads();
        int bid = blockIdx.x - CONV_BLOCKS;
        int stride = HIST_BLOCKS * 256;
        for (int e = bid * 256 + t; e < NNZ_E; e += stride) {
            atomicAdd(&h[cols[e] / DPB], 1);          // pass-1 dest = col
            atomicAdd(&h[256 + rows[e] / DPB], 1);    // pass-2 dest = row
        }
        __syncthreads();
        if (h[t]) atomicAdd(&cnt1[t], h[t]);
        if (h[t + 256]) atomicAdd(&cnt2[t], h[t + 256]);
    }
}

// ---------- phase A: fixed-cap slab regions, block-0-only hist scan ----------
__global__ __launch_bounds__(512) void phaseA_fused(const int* __restrict__ rows,
                                                    const int* __restrict__ cols,
                                                    const float* __restrict__ vals,
                                                    const int* __restrict__ gcnt,
                                                    int* __restrict__ gCur,
                                                    int* __restrict__ sbG,
                                                    uint2* __restrict__ slab) {
    __shared__ uint2 sortedL[2 * EPB2];          // 32 KB
    __shared__ unsigned short bktL[2 * EPB2];    // 8 KB
    __shared__ int cnt[512], off[512], gbase[512];  // 6 KB
    __shared__ int part[512];                    // 2 KB (block 0 only)
    __shared__ int wsum[8];
    __shared__ int totE;
    int t = threadIdx.x;
    int base = blockIdx.x * EPB2;
    cnt[t] = 0;

    // dense-sorted bases: computed ONCE (block 0) and published for phaseB.
    // Other blocks skip entirely (fixed-cap slab regions don't need them).
    if (blockIdx.x == 0) {
        int g = gcnt[t];
        part[t] = g; __syncthreads();
        for (int o = 1; o < 256; o <<= 1) {
            int a = ((t & 255) >= o) ? part[t - o] : 0; __syncthreads();
            part[t] += a; __syncthreads();
        }
        sbG[t] = ((t < 256) ? 0 : NNZ_E) + part[t] - g;
        if (t == 0) sbG[512] = 2 * NNZ_E;
    }
    __syncthreads();

    uint2 eA[4], eB[4];
    int rA[4], rB[4];
    short bA[4], bB[4];
    #pragma unroll
    for (int j = 0; j < 4; j++) {
        int e = base + j * 512 + t;
        if (e < NNZ_E) {
            int r = rows[e], c = cols[e];
            unsigned v = __float_as_uint(vals[e]);
            int b1 = c / DPB, dl1 = c - b1 * DPB;     // pass-1 dest = col, src = row
            int b2 = r / DPB, dl2 = r - b2 * DPB;     // pass-2 dest = row, src = col
            bA[j] = (short)b1;
            eA[j].x = ((unsigned)dl1 << 18) | (unsigned)r;
            eA[j].y = v;
            bB[j] = (short)(256 + b2);
            eB[j].x = ((unsigned)dl2 << 18) | (unsigned)c;
            eB[j].y = v;
            rA[j] = atomicAdd(&cnt[b1], 1);           // rank within (block,bucket)
            rB[j] = atomicAdd(&cnt[256 + b2], 1);
        } else { bA[j] = -1; bB[j] = -1; }
    }
    __syncthreads();
    // hierarchical scan of cnt(512): 2 barriers instead of 18
    int c0 = cnt[t];
    int bs = blk_escan512(c0, t, wsum);
    off[t] = bs;
    if (t == 511) totE = bs + c0;
    __syncthreads();
    // rank-based scatter into LDS: no second atomic pass
    #pragma unroll
    for (int j = 0; j < 4; j++) {
        if (bA[j] >= 0) {
            int p = off[(int)bA[j]] + rA[j];
            sortedL[p] = eA[j]; bktL[p] = (unsigned short)bA[j];
            p = off[(int)bB[j]] + rB[j];
            sortedL[p] = eB[j]; bktL[p] = (unsigned short)bB[j];
        }
    }
    __syncthreads();
    // reserve slots in this bucket's fixed region
    if (cnt[t] > 0) gbase[t] = atomicAdd(&gCur[t], cnt[t]);
    __syncthreads();
    int nE = totE;
    for (int i = t; i < nE; i += 512) {
        int b = bktL[i];
        slab[((size_t)b << 13) + gbase[b] + (i - off[b])] = sortedL[i];
    }
}

// ---------- phase B dir-1: fixed-cap slab in, dense sorted out ----------
__global__ __launch_bounds__(512) void phaseB1(const uint2* __restrict__ slab,
                                               const int* __restrict__ gcnt,
                                               const int* __restrict__ sbG,
                                               int* __restrict__ offs1,
                                               uint2* __restrict__ sorted) {
    __shared__ int cnt[DPB], sc[DPB], cur[DPB], wsum[8];
    int b = blockIdx.x, t = threadIdx.x;     // b in [0, 256): dir-1 buckets
    int n = gcnt[b];
    const uint2* sl = slab + ((size_t)b << 13);
    int sb = sbG[b];
    for (int d = t; d < DPB; d += 512) cnt[d] = 0;
    __syncthreads();
    bool fast = (n <= 512 * MAXE);   // Poisson(5860): always true; guard anyway
    uint2 ent[MAXE]; int rk[MAXE];
    if (fast) {
        #pragma unroll
        for (int k = 0; k < MAXE; k++) {           // static idx -> registers (rule #20)
            int i = t + k * 512;
            bool valid = i < n;
            uint2 e = valid ? sl[i] : make_uint2(0u, 0u);
            ent[k] = e;
            rk[k] = valid ? atomicAdd(&cnt[e.x >> 18], 1) : 0;
        }
    } else {
        for (int i = t; i < n; i += 512)
            atomicAdd(&cnt[sl[i].x >> 18], 1);
    }
    __syncthreads();
    int d0 = 2 * t;
    int c0 = (d0     < DPB) ? cnt[d0]     : 0;
    int c1 = (d0 + 1 < DPB) ? cnt[d0 + 1] : 0;
    int bs = blk_escan512(c0 + c1, t, wsum);
    if (d0     < DPB) { sc[d0]     = bs;      cur[d0]     = bs; }
    if (d0 + 1 < DPB) { sc[d0 + 1] = bs + c0; cur[d0 + 1] = bs + c0; }
    __syncthreads();
    int destBase = b * DPB;
    for (int d = t; d < DPB; d += 512) {
        int dd = destBase + d;
        if (dd <= N_TOTAL) offs1[dd] = sb + sc[d];
    }
    if (fast) {
        #pragma unroll
        for (int k = 0; k < MAXE; k++) {
            int i = t + k * 512;
            if (i < n) {
                int dl = ent[k].x >> 18;
                sorted[sb + sc[dl] + rk[k]] = make_uint2(ent[k].x & 0x3FFFF, ent[k].y);
            }
        }
    } else {
        for (int i = t; i < n; i += 512) {
            uint2 e = sl[i];
            int dl = e.x >> 18;
            int p = atomicAdd(&cur[dl], 1);
            sorted[sb + p] = make_uint2(e.x & 0x3FFFF, e.y);
        }
    }
}

// ---------- fused: phaseB dir-2 (blocks 0..255, 2-pass low-VGPR) || gather1 ----------
__global__ __launch_bounds__(512) void phaseB2_gather1(const uint2* __restrict__ slab,
                                                       const int* __restrict__ gcnt,
                                                       const int* __restrict__ sbG,
                                                       int* __restrict__ offs2,
                                                       uint2* __restrict__ sorted,
                                                       const uint* __restrict__ egoBf,
                                                       const int* __restrict__ offs1,
                                                       uint* __restrict__ hBf) {
    __shared__ int cnt[DPB], sc[DPB], cur[DPB], wsum[8];
    int t = threadIdx.x;
    if (blockIdx.x < NBUCK) {
        // ---- phaseB dir-2 ----
        int b = blockIdx.x + NBUCK;
        int n = gcnt[b];
        const uint2* sl = slab + ((size_t)b << 13);
        int sb = sbG[b];
        for (int d = t; d < DPB; d += 512) cnt[d] = 0;
        __syncthreads();
        for (int i = t; i < n; i += 512)
            atomicAdd(&cnt[sl[i].x >> 18], 1);
        __syncthreads();
        int d0 = 2 * t;
        int c0 = (d0     < DPB) ? cnt[d0]     : 0;
        int c1 = (d0 + 1 < DPB) ? cnt[d0 + 1] : 0;
        int bs = blk_escan512(c0 + c1, t, wsum);
        if (d0     < DPB) { sc[d0]     = bs;      cur[d0]     = bs; }
        if (d0 + 1 < DPB) { sc[d0 + 1] = bs + c0; cur[d0 + 1] = bs + c0; }
        __syncthreads();
        int destBase = blockIdx.x * DPB;
        for (int d = t; d < DPB; d += 512) {
            int dd = destBase + d;
            if (dd <= N_TOTAL) offs2[dd] = sb + sc[d];
        }
        for (int i = t; i < n; i += 512) {
            uint2 e = sl[i];
            int dl = e.x >> 18;
            int p = atomicAdd(&cur[dl], 1);
            sorted[sb + p] = make_uint2(e.x & 0x3FFFF, e.y);
        }
    } else {
        // ---- gather1: 8 rows/block, 512 threads ----
        int lane = t & 63;
        int row = (blockIdx.x - NBUCK) * 8 + (t >> 6);   // exact: 18750*8 = N_TOTAL
        int row_u = __builtin_amdgcn_readfirstlane(row);
        float ax = 0.f, ay = 0.f, bx = 0.f, by = 0.f;
        gather_row(egoBf, offs1, sorted, row_u, lane, ax, ay, bx, by);
        hBf[(size_t)row_u * 64 + lane] = pack_bf16(ax + bx, ay + by);
    }
}

// ---------- gather 2 + LN + residual: SGPR metadata, saddr gathers ----------
__global__ __launch_bounds__(256) void gather2_ln(const uint* __restrict__ hBf,
                                                  const int* __restrict__ offs,
                                                  const uint2* __restrict__ edges,
                                                  const uint* __restrict__ egoBf,
                                                  const float* __restrict__ gamma,
                                                  const float* __restrict__ beta,
                                                  float* __restrict__ out) {
    int lane = threadIdx.x & 63;
    int row = blockIdx.x * 4 + (threadIdx.x >> 6);
    int row_u = __builtin_amdgcn_readfirstlane(row);
    float ax = 0.f, ay = 0.f, bx = 0.f, by = 0.f;
    gather_row(hBf, offs, edges, row_u, lane, ax, ay, bx, by);
    float2 acc = make_float2(ax + bx, ay + by);
    float s = acc.x + acc.y;
    float sq = acc.x * acc.x + acc.y * acc.y;
    #pragma unroll
    for (int o = 1; o <= 16; o <<= 1) {
        s  += __shfl_xor(s, o, 64);
        sq += __shfl_xor(sq, o, 64);
    }
    // lanes 0 and 32 hold the two half-sums -> finish with scalar readlanes
    float sT  = rdlane_f(s, 0)  + rdlane_f(s, 32);
    float sqT = rdlane_f(sq, 0) + rdlane_f(sq, 32);
    float mu = sT * (1.0f / DIM);
    float var = sqT * (1.0f / DIM) - mu * mu;
    float rs = rsqrtf(var + 1e-5f);
    float2 g  = ((const float2*)gamma)[lane];
    float2 bb = ((const float2*)beta)[lane];
    unsigned egoW = __builtin_nontemporal_load(&egoBf[(size_t)row_u * 64 + lane]);
    float2 e2 = unpack_bf16(egoW);
    float2 o2;
    o2.x = (acc.x - mu) * rs * g.x + bb.x + e2.x;
    o2.y = (acc.y - mu) * rs * g.y + bb.y + e2.y;
    u64 ow = (u64)__float_as_uint(o2.x) | ((u64)__float_as_uint(o2.y) << 32);
    __builtin_nontemporal_store(ow, (u64*)out + (size_t)row_u * 64 + lane);
}

// ---------- fallback: atomic scatter path (ws too small) ----------
__device__ __forceinline__ void atomic_add_f32(float* p, float v) {
    __hip_atomic_fetch_add(p, v, __ATOMIC_RELAXED, __HIP_MEMORY_SCOPE_AGENT);
}
__global__ void scatter_kernel(const float* __restrict__ src, const float* __restrict__ vals,
                               const int* __restrict__ gidx, const int* __restrict__ sidx,
                               float* __restrict__ dst, int nnz) {
    int gid = blockIdx.x * blockDim.x + threadIdx.x;
    int e = gid >> 5, lane = gid & 31;
    if (e >= nnz) return;
    float v = vals[e];
    float4 x = ((const float4*)(src + (size_t)gidx[e] * DIM))[lane];
    float* d = dst + (size_t)sidx[e] * DIM + lane * 4;
    atomic_add_f32(d + 0, v * x.x); atomic_add_f32(d + 1, v * x.y);
    atomic_add_f32(d + 2, v * x.z); atomic_add_f32(d + 3, v * x.w);
}
__global__ void ln_residual_kernel(const float* __restrict__ h2, const float* __restrict__ ego,
                                   const float* __restrict__ gamma, const float* __restrict__ beta,
                                   float* __restrict__ out, int nrows) {
    int gid = blockIdx.x * blockDim.x + threadIdx.x;
    int row = gid >> 6, lane = gid & 63;
    if (row >= nrows) return;
    float2 x = ((const float2*)(h2 + (size_t)row * DIM))[lane];
    float s = x.x + x.y, sq = x.x * x.x + x.y * x.y;
    #pragma unroll
    for (int o = 32; o > 0; o >>= 1) { s += __shfl_xor(s, o, 64); sq += __shfl_xor(sq, o, 64); }
    float mu = s * (1.0f / DIM), var = sq * (1.0f / DIM) - mu * mu;
    float rs = rsqrtf(var + 1e-5f);
    float2 eg = ((const float2*)(ego + (size_t)row * DIM))[lane];
    float2 g = ((const float2*)gamma)[lane], b = ((const float2*)beta)[lane];
    float2 o2;
    o2.x = (x.x - mu) * rs * g.x + b.x + eg.x;
    o2.y = (x.y - mu) * rs * g.y + b.y + eg.y;
    ((float2*)(out + (size_t)row * DIM))[lane] = o2;
}

// ---------- launch ----------
extern "C" void kernel_launch(void* const* d_in, const int* in_sizes, int n_in,
                              void* d_out, int out_size, void* d_ws, size_t ws_size,
                              hipStream_t stream) {
    const float* ego   = (const float*)d_in[0];
    const float* vals  = (const float*)d_in[1];
    const float* gamma = (const float*)d_in[2];
    const float* beta  = (const float*)d_in[3];
    const int*   rows  = (const int*)d_in[4];
    const int*   cols  = (const int*)d_in[5];
    float* out = (float*)d_out;

    const size_t EGO_BF_B = (size_t)N_TOTAL * DIM * 2;               // 38.4 MB
    const size_t H_BF_B   = (size_t)N_TOTAL * DIM * 2;               // 38.4 MB
    const size_t SORT_B   = (size_t)2 * NNZ_E * sizeof(uint2);       // 24 MB
    const size_t OFFS_B   = ((size_t)N_TOTAL + 16) * sizeof(int);    // ~0.6 MB each
    const size_t SMALL    = 16384;
    const size_t REQ = EGO_BF_B + H_BF_B + SORT_B + 2 * OFFS_B + SMALL;   // ~102 MB
    const size_t H_FP32_B = (size_t)N_TOTAL * DIM * sizeof(float);   // fallback: 76.8 MB

    char* w = (char*)d_ws;
    uint* egoBf   = (uint*)w;   w += EGO_BF_B;
    uint* hBf     = (uint*)w;   w += H_BF_B;
    uint2* sorted = (uint2*)w;  w += SORT_B;
    int* offs1    = (int*)w;    w += OFFS_B;
    int* offs2    = (int*)w;    w += OFFS_B;
    int* cntArr   = (int*)w;    w += 512 * sizeof(int);   // cntArr + gc contiguous: one memset
    int* gc       = (int*)w;    w += 512 * sizeof(int);
    int* sb       = (int*)w;    w += 516 * sizeof(int);
    uint2* slab   = (uint2*)d_out;    // 512*8192*8 = 33.5 MB scratch in 76.8 MB output;
                                      // dead before gather2_ln writes out

    if (ws_size >= REQ) {
        (void)hipMemsetAsync(cntArr, 0, 1024 * sizeof(int), stream);
        conv_hist<<<CONV_BLOCKS + HIST_BLOCKS, 256, 0, stream>>>(ego, egoBf, rows, cols,
                                                                 cntArr, cntArr + 256);
        phaseA_fused<<<A2_BLOCKS, 512, 0, stream>>>(rows, cols, vals, cntArr, gc, sb, slab);
        phaseB1<<<NBUCK, 512, 0, stream>>>(slab, cntArr, sb, offs1, sorted);
        phaseB2_gather1<<<NBUCK + G1_BLOCKS, 512, 0, stream>>>(slab, cntArr, sb, offs2,
                                                               sorted, egoBf, offs1, hBf);
        gather2_ln<<<N_TOTAL / 4, 256, 0, stream>>>(hBf, offs2, sorted, egoBf,
                                                    gamma, beta, out);
    } else {
        float* h = (float*)d_ws;            // fallback: fp32 h at ws start
        (void)hipMemsetAsync(h, 0, H_FP32_B, stream);
        (void)hipMemsetAsync(out, 0, H_FP32_B, stream);
        long total = (long)NNZ_E * 32;
        int grid = (int)((total + 255) / 256);
        scatter_kernel<<<grid, 256, 0, stream>>>(ego, vals, rows, cols, h, NNZ_E);
        scatter_kernel<<<grid, 256, 0, stream>>>(h, vals, cols, rows, out, NNZ_E);
        int lngrid = (N_TOTAL * 64 + 255) / 256;
        ln_residual_kernel<<<lngrid, 256, 0, stream>>>(out, ego, gamma, beta, out, N_TOTAL);
    }
}

// Round 13
// 323.918 us; speedup vs baseline: 15.9437x; 1.0309x over previous
//
#include <hip/hip_runtime.h>

#define N_TOTAL 150000
#define DIM 128
#define NNZ_E 1500000
#define NBUCK 256
#define DPB 586                 // dests per bucket: 256*586 = 150016 >= 150000
#define EPB2 2048               // edges per phase-A block (emits 2 entries each)
#define NB_A ((NNZ_E + EPB2 - 1) / EPB2)   // 733 phaseA blocks
#define NB_H 256                // hist blocks (512 threads each)
#define NB_C 4688               // conv blocks: ceil(2400000/512)
#define MAXE 16                 // phaseB register slots/thread: 512*16=8192 >= max bucket n
#define SLAB_CAP 8192           // fixed slab slots/bucket (Poisson(5860): 30-sigma margin)

typedef unsigned long long u64;
typedef unsigned uvec16 __attribute__((ext_vector_type(16)));
typedef unsigned uvec2  __attribute__((ext_vector_type(2)));

// ---------- bf16 pack/unpack (RNE) ----------
__device__ __forceinline__ unsigned pack_bf16_bits(unsigned ua, unsigned ub) {
    ua = (ua + 0x7FFFu + ((ua >> 16) & 1u)) >> 16;
    ub = (ub + 0x7FFFu + ((ub >> 16) & 1u)) >> 16;
    return ua | (ub << 16);
}
__device__ __forceinline__ unsigned pack_bf16(float a, float b) {
    return pack_bf16_bits(__float_as_uint(a), __float_as_uint(b));
}
__device__ __forceinline__ float2 unpack_bf16(unsigned u) {
    return make_float2(__uint_as_float(u << 16), __uint_as_float(u & 0xFFFF0000u));
}
__device__ __forceinline__ float rdlane_f(float x, int l) {
    return __uint_as_float((unsigned)__builtin_amdgcn_readlane((int)__float_as_uint(x), l));
}

// ---------- hierarchical scan: wave shfl-scan + 8-wave fixup (2 barriers) ----------
__device__ __forceinline__ int wave_iscan(int v, int lane) {
    #pragma unroll
    for (int o = 1; o < 64; o <<= 1) {
        int u = __shfl_up(v, o, 64);
        if (lane >= o) v += u;
    }
    return v;
}
// exclusive scan of one value/thread across 512 threads; wsum[8] in LDS
__device__ __forceinline__ int blk_escan512(int v, int t, int* wsum) {
    int lane = t & 63, wv = t >> 6;
    int inc = wave_iscan(v, lane);
    if (lane == 63) wsum[wv] = inc;
    __syncthreads();
    if (t < 64) {
        int x = (t < 8) ? wsum[t] : 0;
        int p = wave_iscan(x, t);
        if (t < 8) wsum[t] = p - x;          // exclusive wave prefix
    }
    __syncthreads();
    return wsum[wv] + inc - v;
}

// ---------- scalar-pipe metadata loads (wave-uniform) ----------
__device__ __forceinline__ void sload_pair(uvec16 &a, uvec16 &b, const void* p) {
    asm volatile("s_load_dwordx16 %0, %2, 0x0\n\t"
                 "s_load_dwordx16 %1, %2, 0x40\n\t"
                 "s_waitcnt lgkmcnt(0)"
                 : "=&s"(a), "=&s"(b) : "s"(p) : "memory");
}
__device__ __forceinline__ void sload_be(uvec2 &r, const void* p) {
    asm volatile("s_load_dwordx2 %0, %1, 0x0\n\t"
                 "s_waitcnt lgkmcnt(0)"
                 : "=&s"(r) : "s"(p) : "memory");
}

// process 8 edges from an SGPR chunk; lim = valid count (scalar).
// Invalid slots: index AND weight gated scalar-side -> load row 0 (L1-hot).
// Loads stay branchless -> batch issues in parallel (round-5 lesson).
__device__ __forceinline__ void chunk8(const uvec16 &m, int lim, int lane,
                                       const uint* __restrict__ srcBf,
                                       float &ax, float &ay, float &bx, float &by) {
    #pragma unroll
    for (int j = 0; j < 8; j++) {
        unsigned sx = (j < lim) ? (m[2 * j] & 0x3FFFFu) : 0u;
        float vv = (j < lim) ? __uint_as_float(m[2 * j + 1]) : 0.0f;
        const uint* p = srcBf + ((size_t)sx << 6);   // uniform base -> saddr load
        float2 uu = unpack_bf16(p[lane]);
        if (j & 1) { bx += vv * uu.x; by += vv * uu.y; }
        else       { ax += vv * uu.x; ay += vv * uu.y; }
    }
}

// shared gather-row body (reads edge metadata into SGPRs, accumulates one row)
__device__ __forceinline__ void gather_row(const uint* __restrict__ srcBf,
                                           const int* __restrict__ offs,
                                           const uint2* __restrict__ edges,
                                           int row_u, int lane,
                                           float &ax, float &ay, float &bx, float &by) {
    uvec2 be;
    sload_be(be, offs + row_u);
    int beg = (int)be[0];
    int n = (int)be[1] - beg;
    const u64* ep = (const u64*)edges + beg;
    uvec16 mA, mB;
    sload_pair(mA, mB, ep);                       // <=256B past region stays in ws
    chunk8(mA, n < 8 ? n : 8, lane, srcBf, ax, ay, bx, by);
    if (n > 8) {
        chunk8(mB, n - 8 < 8 ? n - 8 : 8, lane, srcBf, ax, ay, bx, by);
        if (n > 16) {
            uvec16 mC, mD;
            sload_pair(mC, mD, ep + 16);
            chunk8(mC, n - 16 < 8 ? n - 16 : 8, lane, srcBf, ax, ay, bx, by);
            if (n > 24) {
                chunk8(mD, n - 24 < 8 ? n - 24 : 8, lane, srcBf, ax, ay, bx, by);
                for (int k = 32; k < n; k++) {    // statistically never
                    uint2 e = edges[beg + k];
                    float v = __uint_as_float(e.y);
                    float2 u = unpack_bf16(srcBf[(((size_t)e.x) << 6) + lane]);
                    ax += v * u.x; ay += v * u.y;
                }
            }
        }
    }
}

// ---------- megakernel: phaseA (0..732) || hist (733..988) || conv (989..5676) ----------
// All three parts are mutually independent: phaseA uses fixed-cap slab regions
// (no histogram needed); hist feeds phaseB only; conv feeds the gathers only.
__global__ __launch_bounds__(512) void mega(const float* __restrict__ in,
                                            uint* __restrict__ egoBf,
                                            const int* __restrict__ rows,
                                            const int* __restrict__ cols,
                                            const float* __restrict__ vals,
                                            int* __restrict__ gcnt,
                                            int* __restrict__ gCur,
                                            uint2* __restrict__ slab) {
    __shared__ uint2 sortedL[2 * EPB2];          // 32 KB
    __shared__ unsigned short bktL[2 * EPB2];    // 8 KB
    __shared__ int cntL[512], off[512], gbase[512], wsum[8];
    __shared__ int totE;
    int t = threadIdx.x;
    if (blockIdx.x < NB_A) {
        // ---- phaseA: bin 2048 edges -> fixed-cap slab regions ----
        int base = blockIdx.x * EPB2;
        cntL[t] = 0;
        __syncthreads();
        uint2 eA[4], eB[4];
        int rA[4], rB[4];
        short bA[4], bB[4];
        #pragma unroll
        for (int j = 0; j < 4; j++) {
            int e = base + j * 512 + t;
            if (e < NNZ_E) {
                int r = rows[e], c = cols[e];
                unsigned v = __float_as_uint(vals[e]);
                int b1 = c / DPB, dl1 = c - b1 * DPB;   // pass-1 dest = col, src = row
                int b2 = r / DPB, dl2 = r - b2 * DPB;   // pass-2 dest = row, src = col
                bA[j] = (short)b1;
                eA[j].x = ((unsigned)dl1 << 18) | (unsigned)r;
                eA[j].y = v;
                bB[j] = (short)(256 + b2);
                eB[j].x = ((unsigned)dl2 << 18) | (unsigned)c;
                eB[j].y = v;
                rA[j] = atomicAdd(&cntL[b1], 1);        // rank within (block,bucket)
                rB[j] = atomicAdd(&cntL[256 + b2], 1);
            } else { bA[j] = -1; bB[j] = -1; }
        }
        __syncthreads();
        int c0 = cntL[t];
        int bs = blk_escan512(c0, t, wsum);
        off[t] = bs;
        if (t == 511) totE = bs + c0;
        __syncthreads();
        #pragma unroll
        for (int j = 0; j < 4; j++) {
            if (bA[j] >= 0) {
                int p = off[(int)bA[j]] + rA[j];
                sortedL[p] = eA[j]; bktL[p] = (unsigned short)bA[j];
                p = off[(int)bB[j]] + rB[j];
                sortedL[p] = eB[j]; bktL[p] = (unsigned short)bB[j];
            }
        }
        __syncthreads();
        if (cntL[t] > 0) gbase[t] = atomicAdd(&gCur[t], cntL[t]);
        __syncthreads();
        int nE = totE;
        for (int i = t; i < nE; i += 512) {
            int b = bktL[i];
            slab[((size_t)b << 13) + gbase[b] + (i - off[b])] = sortedL[i];
        }
    } else if (blockIdx.x < NB_A + NB_H) {
        // ---- coarse histogram (LDS-aggregated) ----
        cntL[t] = 0;
        __syncthreads();
        int bid = blockIdx.x - NB_A;
        int stride = NB_H * 512;
        for (int e = bid * 512 + t; e < NNZ_E; e += stride) {
            atomicAdd(&cntL[cols[e] / DPB], 1);         // dir-1 dest = col
            atomicAdd(&cntL[256 + rows[e] / DPB], 1);   // dir-2 dest = row
        }
        __syncthreads();
        if (cntL[t]) atomicAdd(&gcnt[t], cntL[t]);
    } else {
        // ---- conv: ego fp32 -> packed bf16 ----
        int i = (blockIdx.x - NB_A - NB_H) * 512 + t;
        if (i < N_TOTAL * DIM / 8) {
            const u64* in8 = (const u64*)in;
            u64 w0 = __builtin_nontemporal_load(&in8[4 * i + 0]);
            u64 w1 = __builtin_nontemporal_load(&in8[4 * i + 1]);
            u64 w2 = __builtin_nontemporal_load(&in8[4 * i + 2]);
            u64 w3 = __builtin_nontemporal_load(&in8[4 * i + 3]);
            uint4 o;
            o.x = pack_bf16_bits((unsigned)w0, (unsigned)(w0 >> 32));
            o.y = pack_bf16_bits((unsigned)w1, (unsigned)(w1 >> 32));
            o.z = pack_bf16_bits((unsigned)w2, (unsigned)(w2 >> 32));
            o.w = pack_bf16_bits((unsigned)w3, (unsigned)(w3 >> 32));
            ((uint4*)egoBf)[i] = o;
        }
    }
}

// ---------- phase B (both dirs, 512 blocks): self-scanned bases, rank emit ----------
__global__ __launch_bounds__(512) void phaseB(const uint2* __restrict__ slab,
                                              const int* __restrict__ gcnt,
                                              int* __restrict__ offs1,
                                              int* __restrict__ offs2,
                                              uint2* __restrict__ sorted) {
    __shared__ int cnt[DPB], sc[DPB], cur[DPB], part[512], wsum[8];
    int b = blockIdx.x, t = threadIdx.x;
    // each block redundantly scans the 512 bucket counts (total dir1 = NNZ_E,
    // so the plain exclusive prefix IS the absolute base into sorted[])
    int g = gcnt[t];
    int pre = blk_escan512(g, t, wsum);
    part[t] = pre;
    __syncthreads();
    int sb = part[b];
    int n = gcnt[b];
    const uint2* sl = slab + ((size_t)b << 13);
    for (int d = t; d < DPB; d += 512) cnt[d] = 0;
    __syncthreads();
    bool fast = (n <= 512 * MAXE);   // Poisson(5860): always true; guard anyway
    uint2 ent[MAXE]; int rk[MAXE];
    if (fast) {
        #pragma unroll
        for (int k = 0; k < MAXE; k++) {           // static idx -> registers (rule #20)
            int i = t + k * 512;
            bool valid = i < n;
            uint2 e = valid ? sl[i] : make_uint2(0u, 0u);
            ent[k] = e;
            rk[k] = valid ? atomicAdd(&cnt[e.x >> 18], 1) : 0;
        }
    } else {
        for (int i = t; i < n; i += 512)
            atomicAdd(&cnt[sl[i].x >> 18], 1);
    }
    __syncthreads();
    int d0 = 2 * t;
    int c0 = (d0     < DPB) ? cnt[d0]     : 0;
    int c1 = (d0 + 1 < DPB) ? cnt[d0 + 1] : 0;
    int bs = blk_escan512(c0 + c1, t, wsum);
    if (d0     < DPB) { sc[d0]     = bs;      cur[d0]     = bs; }
    if (d0 + 1 < DPB) { sc[d0 + 1] = bs + c0; cur[d0 + 1] = bs + c0; }
    __syncthreads();
    int destBase = (b & 255) * DPB;
    int* offs = (b < NBUCK) ? offs1 : offs2;
    for (int d = t; d < DPB; d += 512) {
        int dd = destBase + d;
        if (dd <= N_TOTAL) offs[dd] = sb + sc[d];   // absolute index into sorted[]
    }
    if (fast) {
        #pragma unroll
        for (int k = 0; k < MAXE; k++) {
            int i = t + k * 512;
            if (i < n) {
                int dl = ent[k].x >> 18;
                sorted[sb + sc[dl] + rk[k]] = make_uint2(ent[k].x & 0x3FFFF, ent[k].y);
            }
        }
    } else {
        for (int i = t; i < n; i += 512) {
            uint2 e = sl[i];
            int dl = e.x >> 18;
            int p = atomicAdd(&cur[dl], 1);
            sorted[sb + p] = make_uint2(e.x & 0x3FFFF, e.y);
        }
    }
}

// ---------- gather 1: 8 rows/block, SGPR metadata, saddr gathers ----------
__global__ __launch_bounds__(512) void gather1(const uint* __restrict__ srcBf,
                                               const int* __restrict__ offs,
                                               const uint2* __restrict__ edges,
                                               uint* __restrict__ dstBf) {
    int lane = threadIdx.x & 63;
    int row = blockIdx.x * 8 + (threadIdx.x >> 6);   // exact: 18750*8 = N_TOTAL
    int row_u = __builtin_amdgcn_readfirstlane(row);
    float ax = 0.f, ay = 0.f, bx = 0.f, by = 0.f;
    gather_row(srcBf, offs, edges, row_u, lane, ax, ay, bx, by);
    dstBf[(size_t)row_u * 64 + lane] = pack_bf16(ax + bx, ay + by);
}

// ---------- gather 2 + LN + residual: SGPR metadata, saddr gathers ----------
__global__ __launch_bounds__(256) void gather2_ln(const uint* __restrict__ hBf,
                                                  const int* __restrict__ offs,
                                                  const uint2* __restrict__ edges,
                                                  const uint* __restrict__ egoBf,
                                                  const float* __restrict__ gamma,
                                                  const float* __restrict__ beta,
                                                  float* __restrict__ out) {
    int lane = threadIdx.x & 63;
    int row = blockIdx.x * 4 + (threadIdx.x >> 6);
    int row_u = __builtin_amdgcn_readfirstlane(row);
    float ax = 0.f, ay = 0.f, bx = 0.f, by = 0.f;
    gather_row(hBf, offs, edges, row_u, lane, ax, ay, bx, by);
    float2 acc = make_float2(ax + bx, ay + by);
    float s = acc.x + acc.y;
    float sq = acc.x * acc.x + acc.y * acc.y;
    #pragma unroll
    for (int o = 1; o <= 16; o <<= 1) {
        s  += __shfl_xor(s, o, 64);
        sq += __shfl_xor(sq, o, 64);
    }
    // lanes 0 and 32 hold the two half-sums -> finish with scalar readlanes
    float sT  = rdlane_f(s, 0)  + rdlane_f(s, 32);
    float sqT = rdlane_f(sq, 0) + rdlane_f(sq, 32);
    float mu = sT * (1.0f / DIM);
    float var = sqT * (1.0f / DIM) - mu * mu;
    float rs = rsqrtf(var + 1e-5f);
    float2 g  = ((const float2*)gamma)[lane];
    float2 bb = ((const float2*)beta)[lane];
    unsigned egoW = __builtin_nontemporal_load(&egoBf[(size_t)row_u * 64 + lane]);
    float2 e2 = unpack_bf16(egoW);
    float2 o2;
    o2.x = (acc.x - mu) * rs * g.x + bb.x + e2.x;
    o2.y = (acc.y - mu) * rs * g.y + bb.y + e2.y;
    u64 ow = (u64)__float_as_uint(o2.x) | ((u64)__float_as_uint(o2.y) << 32);
    __builtin_nontemporal_store(ow, (u64*)out + (size_t)row_u * 64 + lane);
}

// ---------- fallback: atomic scatter path (ws too small) ----------
__device__ __forceinline__ void atomic_add_f32(float* p, float v) {
    __hip_atomic_fetch_add(p, v, __ATOMIC_RELAXED, __HIP_MEMORY_SCOPE_AGENT);
}
__global__ void scatter_kernel(const float* __restrict__ src, const float* __restrict__ vals,
                               const int* __restrict__ gidx, const int* __restrict__ sidx,
                               float* __restrict__ dst, int nnz) {
    int gid = blockIdx.x * blockDim.x + threadIdx.x;
    int e = gid >> 5, lane = gid & 31;
    if (e >= nnz) return;
    float v = vals[e];
    float4 x = ((const float4*)(src + (size_t)gidx[e] * DIM))[lane];
    float* d = dst + (size_t)sidx[e] * DIM + lane * 4;
    atomic_add_f32(d + 0, v * x.x); atomic_add_f32(d + 1, v * x.y);
    atomic_add_f32(d + 2, v * x.z); atomic_add_f32(d + 3, v * x.w);
}
__global__ void ln_residual_kernel(const float* __restrict__ h2, const float* __restrict__ ego,
                                   const float* __restrict__ gamma, const float* __restrict__ beta,
                                   float* __restrict__ out, int nrows) {
    int gid = blockIdx.x * blockDim.x + threadIdx.x;
    int row = gid >> 6, lane = gid & 63;
    if (row >= nrows) return;
    float2 x = ((const float2*)(h2 + (size_t)row * DIM))[lane];
    float s = x.x + x.y, sq = x.x * x.x + x.y * x.y;
    #pragma unroll
    for (int o = 32; o > 0; o >>= 1) { s += __shfl_xor(s, o, 64); sq += __shfl_xor(sq, o, 64); }
    float mu = s * (1.0f / DIM), var = sq * (1.0f / DIM) - mu * mu;
    float rs = rsqrtf(var + 1e-5f);
    float2 eg = ((const float2*)(ego + (size_t)row * DIM))[lane];
    float2 g = ((const float2*)gamma)[lane], b = ((const float2*)beta)[lane];
    float2 o2;
    o2.x = (x.x - mu) * rs * g.x + b.x + eg.x;
    o2.y = (x.y - mu) * rs * g.y + b.y + eg.y;
    ((float2*)(out + (size_t)row * DIM))[lane] = o2;
}

// ---------- launch ----------
extern "C" void kernel_launch(void* const* d_in, const int* in_sizes, int n_in,
                              void* d_out, int out_size, void* d_ws, size_t ws_size,
                              hipStream_t stream) {
    const float* ego   = (const float*)d_in[0];
    const float* vals  = (const float*)d_in[1];
    const float* gamma = (const float*)d_in[2];
    const float* beta  = (const float*)d_in[3];
    const int*   rows  = (const int*)d_in[4];
    const int*   cols  = (const int*)d_in[5];
    float* out = (float*)d_out;

    const size_t EGO_BF_B = (size_t)N_TOTAL * DIM * 2;               // 38.4 MB
    const size_t H_BF_B   = (size_t)N_TOTAL * DIM * 2;               // 38.4 MB
    const size_t SORT_B   = (size_t)2 * NNZ_E * sizeof(uint2);       // 24 MB
    const size_t OFFS_B   = ((size_t)N_TOTAL + 16) * sizeof(int);    // ~0.6 MB each
    const size_t SMALL    = 16384;
    const size_t REQ = EGO_BF_B + H_BF_B + SORT_B + 2 * OFFS_B + SMALL;   // ~102 MB
    const size_t H_FP32_B = (size_t)N_TOTAL * DIM * sizeof(float);   // fallback: 76.8 MB

    char* w = (char*)d_ws;
    uint* egoBf   = (uint*)w;   w += EGO_BF_B;
    uint* hBf     = (uint*)w;   w += H_BF_B;
    uint2* sorted = (uint2*)w;  w += SORT_B;
    int* offs1    = (int*)w;    w += OFFS_B;
    int* offs2    = (int*)w;    w += OFFS_B;
    int* cntArr   = (int*)w;    w += 512 * sizeof(int);   // cntArr + gc contiguous: one memset
    int* gc       = (int*)w;    w += 512 * sizeof(int);
    uint2* slab   = (uint2*)d_out;    // 512*8192*8 = 33.5 MB scratch in 76.8 MB output;
                                      // dead before gather2_ln writes out

    if (ws_size >= REQ) {
        (void)hipMemsetAsync(cntArr, 0, 1024 * sizeof(int), stream);
        mega<<<NB_A + NB_H + NB_C, 512, 0, stream>>>(ego, egoBf, rows, cols, vals,
                                                     cntArr, gc, slab);
        phaseB<<<512, 512, 0, stream>>>(slab, cntArr, offs1, offs2, sorted);
        gather1<<<N_TOTAL / 8, 512, 0, stream>>>(egoBf, offs1, sorted, hBf);
        gather2_ln<<<N_TOTAL / 4, 256, 0, stream>>>(hBf, offs2, sorted, egoBf,
                                                    gamma, beta, out);
    } else {
        float* h = (float*)d_ws;            // fallback: fp32 h at ws start
        (void)hipMemsetAsync(h, 0, H_FP32_B, stream);
        (void)hipMemsetAsync(out, 0, H_FP32_B, stream);
        long total = (long)NNZ_E * 32;
        int grid = (int)((total + 255) / 256);
        scatter_kernel<<<grid, 256, 0, stream>>>(ego, vals, rows, cols, h, NNZ_E);
        scatter_kernel<<<grid, 256, 0, stream>>>(h, vals, cols, rows, out, NNZ_E);
        int lngrid = (N_TOTAL * 64 + 255) / 256;
        ln_residual_kernel<<<lngrid, 256, 0, stream>>>(out, ego, gamma, beta, out, N_TOTAL);
    }
}